// Round 1
// baseline (664.501 us; speedup 1.0000x reference)
//
#include <hip/hip_runtime.h>

// RotaryCrossAttention on MI355X (gfx950).
// Pipeline: k_cvtw (weights->bf16) ; k_mask (mask dtype detect + bitpack)
//           k_qproj  : LN(x_query) @ w_q^T -> Q0 f32 [1024][128]
//           k_kvproj : LN(x_context) @ w_kv^T + rotary -> K bf16 [B][8192][128], Vt bf16 [B][128][8192]
//           k_attn   : per (b, 32-q tile): flash attention, 4 waves key-split, bf16 MFMA 16x16x32
//           k_final  : inverse rotary + mean over queries + @ w_o^T
// ws usage ~73 MB (Q0 0.5M, weights 0.25M, bits 4K, K 32M, Vt 32M, AO 8M).

#define DEV static __device__ __forceinline__

typedef __attribute__((ext_vector_type(4))) float f32x4;
typedef __attribute__((ext_vector_type(8))) short s16x8;

constexpr int NB   = 16;
constexpr int NQ   = 1024;
constexpr int SC   = 8192;   // T*C
constexpr int DIM  = 512;
constexpr int CDIM = 256;
constexpr int DH   = 128;

DEV short f2bf(float x){                       // RNE f32->bf16 (no NaNs in this data)
  unsigned u = __builtin_bit_cast(unsigned, x);
  unsigned r = (u + 0x7FFFu + ((u >> 16) & 1u)) >> 16;
  return (short)r;
}

DEV f32x4 mfma16(s16x8 a, s16x8 b, f32x4 c){
  return __builtin_amdgcn_mfma_f32_16x16x32_bf16(a, b, c, 0, 0, 0);
}

// ---------------- weights f32 -> bf16 ----------------
__global__ void k_cvtw(const float* __restrict__ wq, const float* __restrict__ wkv,
                       short* __restrict__ wqb, short* __restrict__ wkvb){
  int i = blockIdx.x * 256 + threadIdx.x;
  if(i < 128*512) wqb[i]  = f2bf(wq[i]);
  if(i < 256*256) wkvb[i] = f2bf(wkv[i]);
}

// ---------------- mask: detect bool(1B) vs int32(4B) storage, pack to bits ----------------
// Values are 0/1. If int32: bytes at offset%4!=0 (within the first 32KB, valid
// under both layouts) are all zero. If bool: ~half are nonzero.
__global__ void k_mask(const unsigned char* __restrict__ raw, unsigned* __restrict__ bits){
  int t = threadIdx.x;
  int nz = 0;
  for(int i = t; i < 8192; i += 256){
    unsigned w = ((const unsigned*)raw)[i];
    if(w & 0xFFFFFF00u) nz = 1;
  }
  int any = __syncthreads_or(nz);
  bool isInt = (any == 0);
  for(int wi = t; wi < NB*2048/32; wi += 256){
    unsigned out = 0;
    if(isInt){
      const int* p = (const int*)raw;
      for(int j = 0; j < 32; j++) out |= (unsigned)(p[wi*32+j] != 0) << j;
    } else {
      for(int j = 0; j < 32; j++) out |= (unsigned)(raw[wi*32+j] != 0) << j;
    }
    bits[wi] = out;
  }
}

// ---------------- Q projection: LN + GEMM (1024x512 @ 512x128) ----------------
__global__ __launch_bounds__(256) void k_qproj(const float* __restrict__ xq,
                                               const float* __restrict__ lnw, const float* __restrict__ lnb,
                                               const short* __restrict__ wqb, float* __restrict__ Q0){
  const int wid = threadIdx.x >> 6, lane = threadIdx.x & 63;
  const int g = lane >> 4, li = lane & 15;
  const int row0 = blockIdx.x * 64 + wid * 16;

  float mean = 0.f, rstd = 0.f;
  #pragma unroll
  for(int r = 0; r < 16; r++){
    const float* rp = xq + (row0 + r) * DIM;
    f32x4 a = *(const f32x4*)(rp + lane*8);
    f32x4 b = *(const f32x4*)(rp + lane*8 + 4);
    float s = 0.f, sq = 0.f;
    #pragma unroll
    for(int i = 0; i < 4; i++){ s += a[i] + b[i]; sq += a[i]*a[i] + b[i]*b[i]; }
    #pragma unroll
    for(int o = 32; o > 0; o >>= 1){ s += __shfl_xor(s, o); sq += __shfl_xor(sq, o); }
    if(li == r){
      mean = s / DIM;
      float var = sq / DIM - mean*mean;
      rstd = rsqrtf(var + 1e-5f);
    }
  }

  f32x4 acc[8];
  #pragma unroll
  for(int n = 0; n < 8; n++) acc[n] = f32x4{0.f,0.f,0.f,0.f};

  for(int kc = 0; kc < 16; kc++){
    int kd = kc*32 + g*8;
    const float* rp = xq + (row0 + li)*DIM + kd;
    f32x4 a0 = *(const f32x4*)rp;
    f32x4 a1 = *(const f32x4*)(rp + 4);
    f32x4 w0 = *(const f32x4*)(lnw + kd), w1 = *(const f32x4*)(lnw + kd + 4);
    f32x4 b0 = *(const f32x4*)(lnb + kd), b1 = *(const f32x4*)(lnb + kd + 4);
    s16x8 af;
    #pragma unroll
    for(int i = 0; i < 4; i++){
      af[i]   = f2bf((a0[i] - mean)*rstd*w0[i] + b0[i]);
      af[i+4] = f2bf((a1[i] - mean)*rstd*w1[i] + b1[i]);
    }
    #pragma unroll
    for(int n = 0; n < 8; n++){
      s16x8 bf = *(const s16x8*)(wqb + (n*16 + li)*DIM + kd);
      acc[n] = mfma16(af, bf, acc[n]);
    }
  }
  #pragma unroll
  for(int n = 0; n < 8; n++)
    #pragma unroll
    for(int r = 0; r < 4; r++){
      int m = row0 + g*4 + r;
      Q0[m*DH + n*16 + li] = acc[n][r];
    }
}

// ---------------- KV projection: LN + GEMM + rotary -> K and V^T ----------------
__global__ __launch_bounds__(256) void k_kvproj(const float* __restrict__ xc,
                                                const float* __restrict__ lnw, const float* __restrict__ lnb,
                                                const short* __restrict__ wkvb, const float* __restrict__ rc,
                                                short* __restrict__ Kd, short* __restrict__ Vt){
  __shared__ __align__(16) short Klds[128][136];
  __shared__ __align__(16) short Vtlds[128][136];
  const int wid = threadIdx.x >> 6, lane = threadIdx.x & 63;
  const int g = lane >> 4, li = lane & 15;
  const int b = blockIdx.y;
  const int s0 = blockIdx.x * 128;
  const int ws0 = s0 + wid * 32;

  float mean_s[2], rstd_s[2];
  #pragma unroll
  for(int r = 0; r < 32; r++){
    const float* rp = xc + (b*SC + ws0 + r)*CDIM;
    f32x4 a = *(const f32x4*)(rp + lane*4);
    float s = a[0]+a[1]+a[2]+a[3];
    float sq = a[0]*a[0]+a[1]*a[1]+a[2]*a[2]+a[3]*a[3];
    #pragma unroll
    for(int o = 32; o > 0; o >>= 1){ s += __shfl_xor(s, o); sq += __shfl_xor(sq, o); }
    if(li == (r & 15)){
      float m = s / CDIM;
      float var = sq / CDIM - m*m;
      if((r >> 4) == 0){ mean_s[0] = m; rstd_s[0] = rsqrtf(var + 1e-5f); }
      else             { mean_s[1] = m; rstd_s[1] = rsqrtf(var + 1e-5f); }
    }
  }

  f32x4 acc[16][2];
  #pragma unroll
  for(int n = 0; n < 16; n++){ acc[n][0] = f32x4{0.f,0.f,0.f,0.f}; acc[n][1] = f32x4{0.f,0.f,0.f,0.f}; }

  for(int kc = 0; kc < 8; kc++){
    int kd = kc*32 + g*8;
    f32x4 w0 = *(const f32x4*)(lnw + kd), w1 = *(const f32x4*)(lnw + kd + 4);
    f32x4 b0 = *(const f32x4*)(lnb + kd), b1 = *(const f32x4*)(lnb + kd + 4);
    s16x8 af[2];
    #pragma unroll
    for(int sub = 0; sub < 2; sub++){
      const float* rp = xc + (b*SC + ws0 + sub*16 + li)*CDIM + kd;
      f32x4 a0 = *(const f32x4*)rp;
      f32x4 a1 = *(const f32x4*)(rp + 4);
      float mn = mean_s[sub], rs = rstd_s[sub];
      #pragma unroll
      for(int i = 0; i < 4; i++){
        af[sub][i]   = f2bf((a0[i]-mn)*rs*w0[i] + b0[i]);
        af[sub][i+4] = f2bf((a1[i]-mn)*rs*w1[i] + b1[i]);
      }
    }
    #pragma unroll
    for(int nt = 0; nt < 16; nt++){
      s16x8 bf = *(const s16x8*)(wkvb + (nt*16 + li)*CDIM + kd);
      acc[nt][0] = mfma16(af[0], bf, acc[nt][0]);
      acc[nt][1] = mfma16(af[1], bf, acc[nt][1]);
    }
  }

  // rotary + stage (k rows, v transposed)
  #pragma unroll
  for(int nt = 0; nt < 8; nt++){
    #pragma unroll
    for(int sub = 0; sub < 2; sub++){
      #pragma unroll
      for(int r = 0; r < 4; r++){
        int srow = wid*32 + sub*16 + g*4 + r;      // 0..127
        int d = nt*16 + li;                        // 0..127
        float f = rc[(b*SC + s0 + srow)*DH + d];
        float sn, cs; __sincosf(f, &sn, &cs);
        float kv = acc[nt][sub][r];
        float kp = __shfl_xor(kv, 1);
        float ky = (d & 1) ? (kv*cs + kp*sn) : (kv*cs - kp*sn);
        Klds[srow][d] = f2bf(ky);
        float vv = acc[nt+8][sub][r];
        float vp = __shfl_xor(vv, 1);
        float vy = (d & 1) ? (vv*cs + vp*sn) : (vv*cs - vp*sn);
        Vtlds[d][srow] = f2bf(vy);
      }
    }
  }
  __syncthreads();
  for(int c = threadIdx.x; c < 2048; c += 256){
    int row = c >> 4, col = (c & 15) * 8;
    s16x8 kv = *(const s16x8*)&Klds[row][col];
    *(s16x8*)(Kd + (b*SC + s0 + row)*DH + col) = kv;
    s16x8 vv = *(const s16x8*)&Vtlds[row][col];
    *(s16x8*)(Vt + (b*DH + row)*SC + s0 + col) = vv;
  }
}

// ---------------- attention ----------------
// block: 32 q rows, 4 waves key-split (2048 keys each, = mask period).
// St = mfma(K, Q) -> St[k,q] (col=lane&15 is q); softmax reduce = 2 shuffles;
// P -> per-wave LDS -> B-frag; out^T[d,q] = mfma(Vt, P).
__global__ __launch_bounds__(256) void k_attn(const float* __restrict__ Q0, const float* __restrict__ rq,
                                              const short* __restrict__ Kd, const short* __restrict__ Vt,
                                              const unsigned* __restrict__ bits, float* __restrict__ AO){
  __shared__ __align__(16) short Plds[4][2][16][40];
  __shared__ float sOut[4][128][33];
  __shared__ float sM[4][2][16];
  __shared__ float sL[4][2][16];
  const int wid = threadIdx.x >> 6, lane = threadIdx.x & 63;
  const int g = lane >> 4, li = lane & 15;
  const int b = blockIdx.y;
  const int q0 = blockIdx.x * 32;
  constexpr float C2 = 0.08838834764831845f * 1.4426950408889634f; // scale * log2(e)

  // Q fragments with rotary applied, bf16
  s16x8 qf[2][4];
  #pragma unroll
  for(int qs = 0; qs < 2; qs++){
    int qrow = q0 + qs*16 + li;
    #pragma unroll
    for(int c = 0; c < 4; c++){
      int d0 = c*32 + g*8;
      const float* qp = Q0 + qrow*DH + d0;
      const float* fp = rq + (b*NQ + qrow)*DH + d0;
      f32x4 x0 = *(const f32x4*)qp,     x1 = *(const f32x4*)(qp+4);
      f32x4 f0 = *(const f32x4*)fp,     f1 = *(const f32x4*)(fp+4);
      float xs[8] = {x0[0],x0[1],x0[2],x0[3],x1[0],x1[1],x1[2],x1[3]};
      float fs[8] = {f0[0],f0[1],f0[2],f0[3],f1[0],f1[1],f1[2],f1[3]};
      #pragma unroll
      for(int i = 0; i < 4; i++){
        float se, ce, so, co;
        __sincosf(fs[2*i],   &se, &ce);
        __sincosf(fs[2*i+1], &so, &co);
        qf[qs][c][2*i]   = f2bf(xs[2*i]*ce   - xs[2*i+1]*se);
        qf[qs][c][2*i+1] = f2bf(xs[2*i+1]*co + xs[2*i]*so);
      }
    }
  }

  float mrun[2] = {-1e30f, -1e30f}, lrun[2] = {0.f, 0.f};
  f32x4 acc[2][8];
  #pragma unroll
  for(int qs = 0; qs < 2; qs++)
    #pragma unroll
    for(int dt = 0; dt < 8; dt++) acc[qs][dt] = f32x4{0.f,0.f,0.f,0.f};

  const short* Kb  = Kd + b*SC*DH;
  const short* Vtb = Vt + b*DH*SC;

  for(int kk = 0; kk < 2048; kk += 32){
    const int kglob = wid*2048 + kk;
    const unsigned mword = bits[b*64 + (kk >> 5)];   // mask index = key % 2048

    f32x4 st[2][2];
    #pragma unroll
    for(int ks = 0; ks < 2; ks++){
      s16x8 kf[4];
      #pragma unroll
      for(int c = 0; c < 4; c++)
        kf[c] = *(const s16x8*)(Kb + (kglob + ks*16 + li)*DH + c*32 + g*8);
      #pragma unroll
      for(int qs = 0; qs < 2; qs++){
        f32x4 s = f32x4{0.f,0.f,0.f,0.f};
        #pragma unroll
        for(int c = 0; c < 4; c++) s = mfma16(kf[c], qf[qs][c], s);
        st[qs][ks] = s;
      }
    }

    #pragma unroll
    for(int qs = 0; qs < 2; qs++){
      float sv[8];
      #pragma unroll
      for(int ks = 0; ks < 2; ks++)
        #pragma unroll
        for(int r = 0; r < 4; r++){
          int k32 = ks*16 + g*4 + r;
          sv[ks*4+r] = ((mword >> k32) & 1u) ? st[qs][ks][r] : -1e30f;
        }
      float mt = sv[0];
      #pragma unroll
      for(int j = 1; j < 8; j++) mt = fmaxf(mt, sv[j]);
      mt = fmaxf(mt, __shfl_xor(mt, 16));
      mt = fmaxf(mt, __shfl_xor(mt, 32));
      float mnew = fmaxf(mrun[qs], mt);
      float alpha = exp2f((mrun[qs] - mnew) * C2);
      mrun[qs] = mnew;
      float p[8], psum = 0.f;
      #pragma unroll
      for(int j = 0; j < 8; j++){ p[j] = exp2f((sv[j] - mnew) * C2); psum += p[j]; }
      psum += __shfl_xor(psum, 16);
      psum += __shfl_xor(psum, 32);
      lrun[qs] = lrun[qs]*alpha + psum;
      #pragma unroll
      for(int dt = 0; dt < 8; dt++) acc[qs][dt] = acc[qs][dt] * alpha;
      #pragma unroll
      for(int ks = 0; ks < 2; ks++){
        unsigned lo = (unsigned)(unsigned short)f2bf(p[ks*4+0]) | ((unsigned)(unsigned short)f2bf(p[ks*4+1]) << 16);
        unsigned hi = (unsigned)(unsigned short)f2bf(p[ks*4+2]) | ((unsigned)(unsigned short)f2bf(p[ks*4+3]) << 16);
        unsigned* wp = (unsigned*)&Plds[wid][qs][li][ks*16 + g*4];
        wp[0] = lo; wp[1] = hi;
      }
    }

    s16x8 pf0 = *(const s16x8*)&Plds[wid][0][li][g*8];
    s16x8 pf1 = *(const s16x8*)&Plds[wid][1][li][g*8];
    #pragma unroll
    for(int dt = 0; dt < 8; dt++){
      s16x8 vf = *(const s16x8*)(Vtb + (dt*16 + li)*SC + kglob + g*8);
      acc[0][dt] = mfma16(vf, pf0, acc[0][dt]);
      acc[1][dt] = mfma16(vf, pf1, acc[1][dt]);
    }
  }

  if(lane < 16){
    sM[wid][0][li] = mrun[0]; sM[wid][1][li] = mrun[1];
    sL[wid][0][li] = lrun[0]; sL[wid][1][li] = lrun[1];
  }
  #pragma unroll
  for(int qs = 0; qs < 2; qs++)
    #pragma unroll
    for(int dt = 0; dt < 8; dt++)
      #pragma unroll
      for(int r = 0; r < 4; r++)
        sOut[wid][dt*16 + g*4 + r][qs*16 + li] = acc[qs][dt][r];
  __syncthreads();

  {
    int q  = threadIdx.x >> 3;            // 0..31
    int dc = (threadIdx.x & 7) * 16;      // 0,16,..,112
    int qs = q >> 4, ql = q & 15;
    float m0 = sM[0][qs][ql], m1 = sM[1][qs][ql], m2 = sM[2][qs][ql], m3 = sM[3][qs][ql];
    float M = fmaxf(fmaxf(m0, m1), fmaxf(m2, m3));
    float a0 = exp2f((m0 - M)*C2), a1 = exp2f((m1 - M)*C2), a2 = exp2f((m2 - M)*C2), a3 = exp2f((m3 - M)*C2);
    float Lt = a0*sL[0][qs][ql] + a1*sL[1][qs][ql] + a2*sL[2][qs][ql] + a3*sL[3][qs][ql];
    float inv = 1.f / Lt;
    float* op = AO + (b*NQ + q0 + q)*DH + dc;
    #pragma unroll
    for(int i = 0; i < 16; i++){
      float o = a0*sOut[0][dc+i][q] + a1*sOut[1][dc+i][q] + a2*sOut[2][dc+i][q] + a3*sOut[3][dc+i][q];
      op[i] = o * inv;
    }
  }
}

// ---------------- final: inverse rotary, mean over queries, @ w_o^T + b_o ----------------
__global__ __launch_bounds__(256) void k_final(const float* __restrict__ AO, const float* __restrict__ rq,
                                               const float* __restrict__ wo, const float* __restrict__ bo,
                                               float* __restrict__ out){
  __shared__ float part[2][128];
  __shared__ float sm[128];
  int b = blockIdx.x;
  int t = threadIdx.x;
  int d = t & 127, h = t >> 7;
  float acc = 0.f;
  for(int n = h; n < NQ; n += 2){
    const float* ap = AO + (b*NQ + n)*DH;
    float x = ap[d], p = ap[d ^ 1];
    float f = rq[(b*NQ + n)*DH + d];
    float sn, cs; __sincosf(f, &sn, &cs);
    acc += (d & 1) ? (x*cs - p*sn) : (x*cs + p*sn);   // rotary with -f
  }
  part[h][d] = acc;
  __syncthreads();
  if(h == 0) sm[d] = (part[0][d] + part[1][d]) * (1.0f / NQ);
  __syncthreads();
  for(int o = t; o < DIM; o += 256){
    float s = bo[o];
    const float* wr = wo + o*DH;
    #pragma unroll 4
    for(int j = 0; j < DH; j++) s += sm[j] * wr[j];
    out[b*DIM + o] = s;
  }
}

extern "C" void kernel_launch(void* const* d_in, const int* in_sizes, int n_in,
                              void* d_out, int out_size, void* d_ws, size_t ws_size,
                              hipStream_t stream){
  const float* xq   = (const float*)d_in[0];
  const float* xc   = (const float*)d_in[1];
  const float* rq   = (const float*)d_in[2];
  const float* rc   = (const float*)d_in[3];
  const unsigned char* mask = (const unsigned char*)d_in[4];
  const float* lnqw = (const float*)d_in[5];
  const float* lnqb = (const float*)d_in[6];
  const float* lncw = (const float*)d_in[7];
  const float* lncb = (const float*)d_in[8];
  const float* wq   = (const float*)d_in[9];
  const float* wkv  = (const float*)d_in[10];
  const float* wo   = (const float*)d_in[11];
  const float* bo   = (const float*)d_in[12];
  float* out = (float*)d_out;

  char* ws = (char*)d_ws;
  size_t off = 0;
  auto alloc = [&](size_t bytes){ void* p = ws + off; off += (bytes + 255) & ~(size_t)255; return p; };
  float*    Q0   = (float*)   alloc((size_t)NQ*DH*4);
  short*    wqb  = (short*)   alloc((size_t)128*512*2);
  short*    wkvb = (short*)   alloc((size_t)256*256*2);
  unsigned* bits = (unsigned*)alloc((size_t)NB*64*4);
  short*    Kd   = (short*)   alloc((size_t)NB*SC*DH*2);
  short*    Vt   = (short*)   alloc((size_t)NB*SC*DH*2);
  float*    AO   = (float*)   alloc((size_t)NB*NQ*DH*4);

  k_cvtw  <<<dim3(256),    dim3(256), 0, stream>>>(wq, wkv, wqb, wkvb);
  k_mask  <<<dim3(1),      dim3(256), 0, stream>>>(mask, bits);
  k_qproj <<<dim3(16),     dim3(256), 0, stream>>>(xq, lnqw, lnqb, wqb, Q0);
  k_kvproj<<<dim3(64,16),  dim3(256), 0, stream>>>(xc, lncw, lncb, wkvb, rc, Kd, Vt);
  k_attn  <<<dim3(32,16),  dim3(256), 0, stream>>>(Q0, rq, Kd, Vt, bits, AO);
  k_final <<<dim3(16),     dim3(256), 0, stream>>>(AO, rq, wo, bo, out);
}

// Round 2
// 532.779 us; speedup vs baseline: 1.2472x; 1.2472x over previous
//
#include <hip/hip_runtime.h>
#include <hip/hip_bf16.h>

// RotaryCrossAttention on MI355X (gfx950).
// v2: attention VALU diet — l via ones-row MFMA (mask folded into V),
//     defer-rescale (THR=3 log2), cvt_pk bf16 packing, XCD-swizzled grid;
//     k_final split into 512-block partial pass + reduce pass.
// Pipeline: k_cvtw ; k_mask ; k_vrow (Vt row128 = mask) ; k_qproj ;
//           k_kvproj (V masked-zeroed) ; k_attn ; k_fin1 ; k_fin2

#define DEV static __device__ __forceinline__

typedef __attribute__((ext_vector_type(4))) float f32x4;
typedef __attribute__((ext_vector_type(8))) short s16x8;

constexpr int NB   = 16;
constexpr int NQ   = 1024;
constexpr int SC   = 8192;   // T*C
constexpr int DIM  = 512;
constexpr int CDIM = 256;
constexpr int DH   = 128;
constexpr int VROWS = 144;   // 128 V rows + row128 = mask ones + 15 dead rows

DEV short f2bf(float x){
  unsigned u = __builtin_bit_cast(unsigned, x);
  unsigned r = (u + 0x7FFFu + ((u >> 16) & 1u)) >> 16;
  return (short)r;
}

DEV unsigned pk2(float a, float b){   // pack 2 f32 -> 2 bf16 (compiler: v_cvt_pk_bf16_f32)
  unsigned short ua = __builtin_bit_cast(unsigned short, __float2bfloat16(a));
  unsigned short ub = __builtin_bit_cast(unsigned short, __float2bfloat16(b));
  return (unsigned)ua | ((unsigned)ub << 16);
}

DEV f32x4 mfma16(s16x8 a, s16x8 b, f32x4 c){
  return __builtin_amdgcn_mfma_f32_16x16x32_bf16(a, b, c, 0, 0, 0);
}

// ---------------- weights f32 -> bf16 ----------------
__global__ void k_cvtw(const float* __restrict__ wq, const float* __restrict__ wkv,
                       short* __restrict__ wqb, short* __restrict__ wkvb){
  int i = blockIdx.x * 256 + threadIdx.x;
  if(i < 128*512) wqb[i]  = f2bf(wq[i]);
  if(i < 256*256) wkvb[i] = f2bf(wkv[i]);
}

// ---------------- mask: detect bool(1B) vs int32(4B), pack to bits ----------------
__global__ void k_mask(const unsigned char* __restrict__ raw, unsigned* __restrict__ bits){
  int t = threadIdx.x;
  int nz = 0;
  for(int i = t; i < 8192; i += 256){
    unsigned w = ((const unsigned*)raw)[i];
    if(w & 0xFFFFFF00u) nz = 1;
  }
  int any = __syncthreads_or(nz);
  bool isInt = (any == 0);
  for(int wi = t; wi < NB*2048/32; wi += 256){
    unsigned out = 0;
    if(isInt){
      const int* p = (const int*)raw;
      for(int j = 0; j < 32; j++) out |= (unsigned)(p[wi*32+j] != 0) << j;
    } else {
      for(int j = 0; j < 32; j++) out |= (unsigned)(raw[wi*32+j] != 0) << j;
    }
    bits[wi] = out;
  }
}

// ---------------- Vt row 128 = mask as bf16 ones ----------------
__global__ void k_vrow(const unsigned* __restrict__ bits, short* __restrict__ Vt){
  int b = blockIdx.y;
  int s = blockIdx.x * 512 + threadIdx.x * 2;
  unsigned w = bits[b*64 + ((s & 2047) >> 5)];
  short2 v;
  v.x = ((w >> ( s      & 31)) & 1u) ? (short)0x3F80 : (short)0;
  v.y = ((w >> ((s + 1) & 31)) & 1u) ? (short)0x3F80 : (short)0;
  *(short2*)(Vt + ((size_t)b*VROWS + 128)*SC + s) = v;
}

// ---------------- Q projection: LN + GEMM (1024x512 @ 512x128) ----------------
__global__ __launch_bounds__(256) void k_qproj(const float* __restrict__ xq,
                                               const float* __restrict__ lnw, const float* __restrict__ lnb,
                                               const short* __restrict__ wqb, float* __restrict__ Q0){
  const int wid = threadIdx.x >> 6, lane = threadIdx.x & 63;
  const int g = lane >> 4, li = lane & 15;
  const int row0 = blockIdx.x * 64 + wid * 16;

  float mean = 0.f, rstd = 0.f;
  #pragma unroll
  for(int r = 0; r < 16; r++){
    const float* rp = xq + (row0 + r) * DIM;
    f32x4 a = *(const f32x4*)(rp + lane*8);
    f32x4 b = *(const f32x4*)(rp + lane*8 + 4);
    float s = 0.f, sq = 0.f;
    #pragma unroll
    for(int i = 0; i < 4; i++){ s += a[i] + b[i]; sq += a[i]*a[i] + b[i]*b[i]; }
    #pragma unroll
    for(int o = 32; o > 0; o >>= 1){ s += __shfl_xor(s, o); sq += __shfl_xor(sq, o); }
    if(li == r){
      mean = s / DIM;
      float var = sq / DIM - mean*mean;
      rstd = rsqrtf(var + 1e-5f);
    }
  }

  f32x4 acc[8];
  #pragma unroll
  for(int n = 0; n < 8; n++) acc[n] = f32x4{0.f,0.f,0.f,0.f};

  for(int kc = 0; kc < 16; kc++){
    int kd = kc*32 + g*8;
    const float* rp = xq + (row0 + li)*DIM + kd;
    f32x4 a0 = *(const f32x4*)rp;
    f32x4 a1 = *(const f32x4*)(rp + 4);
    f32x4 w0 = *(const f32x4*)(lnw + kd), w1 = *(const f32x4*)(lnw + kd + 4);
    f32x4 b0 = *(const f32x4*)(lnb + kd), b1 = *(const f32x4*)(lnb + kd + 4);
    s16x8 af;
    #pragma unroll
    for(int i = 0; i < 4; i++){
      af[i]   = f2bf((a0[i] - mean)*rstd*w0[i] + b0[i]);
      af[i+4] = f2bf((a1[i] - mean)*rstd*w1[i] + b1[i]);
    }
    #pragma unroll
    for(int n = 0; n < 8; n++){
      s16x8 bf = *(const s16x8*)(wqb + (n*16 + li)*DIM + kd);
      acc[n] = mfma16(af, bf, acc[n]);
    }
  }
  #pragma unroll
  for(int n = 0; n < 8; n++)
    #pragma unroll
    for(int r = 0; r < 4; r++){
      int m = row0 + g*4 + r;
      Q0[m*DH + n*16 + li] = acc[n][r];
    }
}

// ---------------- KV projection: LN + GEMM + rotary -> K and V^T (V masked) ----------------
__global__ __launch_bounds__(256) void k_kvproj(const float* __restrict__ xc,
                                                const float* __restrict__ lnw, const float* __restrict__ lnb,
                                                const short* __restrict__ wkvb, const float* __restrict__ rc,
                                                const unsigned* __restrict__ bits,
                                                short* __restrict__ Kd, short* __restrict__ Vt){
  __shared__ __align__(16) short Klds[128][136];
  __shared__ __align__(16) short Vtlds[128][136];
  const int wid = threadIdx.x >> 6, lane = threadIdx.x & 63;
  const int g = lane >> 4, li = lane & 15;
  const int b = blockIdx.y;
  const int s0 = blockIdx.x * 128;
  const int ws0 = s0 + wid * 32;

  float mean_s[2], rstd_s[2];
  #pragma unroll
  for(int r = 0; r < 32; r++){
    const float* rp = xc + (b*SC + ws0 + r)*CDIM;
    f32x4 a = *(const f32x4*)(rp + lane*4);
    float s = a[0]+a[1]+a[2]+a[3];
    float sq = a[0]*a[0]+a[1]*a[1]+a[2]*a[2]+a[3]*a[3];
    #pragma unroll
    for(int o = 32; o > 0; o >>= 1){ s += __shfl_xor(s, o); sq += __shfl_xor(sq, o); }
    if(li == (r & 15)){
      float m = s / CDIM;
      float var = sq / CDIM - m*m;
      if((r >> 4) == 0){ mean_s[0] = m; rstd_s[0] = rsqrtf(var + 1e-5f); }
      else             { mean_s[1] = m; rstd_s[1] = rsqrtf(var + 1e-5f); }
    }
  }

  f32x4 acc[16][2];
  #pragma unroll
  for(int n = 0; n < 16; n++){ acc[n][0] = f32x4{0.f,0.f,0.f,0.f}; acc[n][1] = f32x4{0.f,0.f,0.f,0.f}; }

  for(int kc = 0; kc < 8; kc++){
    int kd = kc*32 + g*8;
    f32x4 w0 = *(const f32x4*)(lnw + kd), w1 = *(const f32x4*)(lnw + kd + 4);
    f32x4 b0 = *(const f32x4*)(lnb + kd), b1 = *(const f32x4*)(lnb + kd + 4);
    s16x8 af[2];
    #pragma unroll
    for(int sub = 0; sub < 2; sub++){
      const float* rp = xc + (b*SC + ws0 + sub*16 + li)*CDIM + kd;
      f32x4 a0 = *(const f32x4*)rp;
      f32x4 a1 = *(const f32x4*)(rp + 4);
      float mn = mean_s[sub], rs = rstd_s[sub];
      #pragma unroll
      for(int i = 0; i < 4; i++){
        af[sub][i]   = f2bf((a0[i]-mn)*rs*w0[i] + b0[i]);
        af[sub][i+4] = f2bf((a1[i]-mn)*rs*w1[i] + b1[i]);
      }
    }
    #pragma unroll
    for(int nt = 0; nt < 16; nt++){
      s16x8 bf = *(const s16x8*)(wkvb + (nt*16 + li)*CDIM + kd);
      acc[nt][0] = mfma16(af[0], bf, acc[nt][0]);
      acc[nt][1] = mfma16(af[1], bf, acc[nt][1]);
    }
  }

  // rotary + stage (k rows, v transposed)
  #pragma unroll
  for(int nt = 0; nt < 8; nt++){
    #pragma unroll
    for(int sub = 0; sub < 2; sub++){
      #pragma unroll
      for(int r = 0; r < 4; r++){
        int srow = wid*32 + sub*16 + g*4 + r;      // 0..127
        int d = nt*16 + li;                        // 0..127
        float f = rc[(b*SC + s0 + srow)*DH + d];
        float sn, cs; __sincosf(f, &sn, &cs);
        float kv = acc[nt][sub][r];
        float kp = __shfl_xor(kv, 1);
        float ky = (d & 1) ? (kv*cs + kp*sn) : (kv*cs - kp*sn);
        Klds[srow][d] = f2bf(ky);
        float vv = acc[nt+8][sub][r];
        float vp = __shfl_xor(vv, 1);
        float vy = (d & 1) ? (vv*cs + vp*sn) : (vv*cs - vp*sn);
        Vtlds[d][srow] = f2bf(vy);
      }
    }
  }
  __syncthreads();
  for(int c = threadIdx.x; c < 2048; c += 256){
    int row = c >> 4, col = (c & 15) * 8;
    s16x8 kv = *(const s16x8*)&Klds[row][col];
    *(s16x8*)(Kd + ((size_t)b*SC + s0 + row)*DH + col) = kv;
    s16x8 vv = *(const s16x8*)&Vtlds[row][col];
    int sa = s0 + col;
    unsigned w = bits[b*64 + ((sa & 2047) >> 5)];
    unsigned mb = (w >> (sa & 31)) & 0xFFu;
    #pragma unroll
    for(int j = 0; j < 8; j++) if(!((mb >> j) & 1u)) vv[j] = 0;
    *(s16x8*)(Vt + ((size_t)b*VROWS + row)*SC + sa) = vv;
  }
}

// ---------------- attention ----------------
// block: 32 q rows, 4 waves key-split (2048 keys each). Swapped QK (St[k,q]).
// l = row 128 of PV acc (Vt ones-row); mask folded into Vt; defer-rescale THR=3.
__global__ __launch_bounds__(256, 2) void k_attn(const float* __restrict__ Q0, const float* __restrict__ rq,
                                                 const short* __restrict__ Kd, const short* __restrict__ Vt,
                                                 float* __restrict__ AO){
  __shared__ __align__(16) short Plds[4][2][16][40];
  __shared__ float sOut[4][65][33];
  __shared__ float sM[4][2][16];
  __shared__ float sB[4][32];
  const int wid = threadIdx.x >> 6, lane = threadIdx.x & 63;
  const int g = lane >> 4, li = lane & 15;
  // XCD swizzle: 512 blocks, 64/XCD, 2 batches per XCD
  const int oid = (blockIdx.x & 7) * 64 + (blockIdx.x >> 3);
  const int b = oid >> 5;
  const int q0 = (oid & 31) * 32;
  constexpr float C2 = 0.08838834764831845f * 1.4426950408889634f; // scale * log2(e)

  // Q fragments with rotary applied, pre-scaled by C2, bf16
  s16x8 qf[2][4];
  #pragma unroll
  for(int qs = 0; qs < 2; qs++){
    int qrow = q0 + qs*16 + li;
    #pragma unroll
    for(int c = 0; c < 4; c++){
      int d0 = c*32 + g*8;
      const float* qp = Q0 + qrow*DH + d0;
      const float* fp = rq + (b*NQ + qrow)*DH + d0;
      f32x4 x0 = *(const f32x4*)qp,     x1 = *(const f32x4*)(qp+4);
      f32x4 f0 = *(const f32x4*)fp,     f1 = *(const f32x4*)(fp+4);
      float xs[8] = {x0[0],x0[1],x0[2],x0[3],x1[0],x1[1],x1[2],x1[3]};
      float fs[8] = {f0[0],f0[1],f0[2],f0[3],f1[0],f1[1],f1[2],f1[3]};
      #pragma unroll
      for(int i = 0; i < 4; i++){
        float se, ce, so, co;
        __sincosf(fs[2*i],   &se, &ce);
        __sincosf(fs[2*i+1], &so, &co);
        qf[qs][c][2*i]   = f2bf((xs[2*i]*ce   - xs[2*i+1]*se) * C2);
        qf[qs][c][2*i+1] = f2bf((xs[2*i+1]*co + xs[2*i]*so) * C2);
      }
    }
  }

  float mrun[2] = {-1e30f, -1e30f};
  f32x4 acc[2][9];
  #pragma unroll
  for(int qs = 0; qs < 2; qs++)
    #pragma unroll
    for(int dt = 0; dt < 9; dt++) acc[qs][dt] = f32x4{0.f,0.f,0.f,0.f};

  const short* Kp  = Kd + ((size_t)b*SC + wid*2048)*DH;
  const short* Vp  = Vt + (size_t)b*VROWS*SC + wid*2048;

  for(int kk = 0; kk < 2048; kk += 32){
    f32x4 st[2][2];
    #pragma unroll
    for(int ks = 0; ks < 2; ks++){
      s16x8 kf[4];
      #pragma unroll
      for(int c = 0; c < 4; c++)
        kf[c] = *(const s16x8*)(Kp + (ks*16 + li)*DH + c*32 + g*8);
      #pragma unroll
      for(int qs = 0; qs < 2; qs++){
        f32x4 s = f32x4{0.f,0.f,0.f,0.f};
        #pragma unroll
        for(int c = 0; c < 4; c++) s = mfma16(kf[c], qf[qs][c], s);
        st[qs][ks] = s;
      }
    }

    #pragma unroll
    for(int qs = 0; qs < 2; qs++){
      float mt = fmaxf(fmaxf(fmaxf(st[qs][0][0], st[qs][0][1]), fmaxf(st[qs][0][2], st[qs][0][3])),
                       fmaxf(fmaxf(st[qs][1][0], st[qs][1][1]), fmaxf(st[qs][1][2], st[qs][1][3])));
      mt = fmaxf(mt, __shfl_xor(mt, 16));
      mt = fmaxf(mt, __shfl_xor(mt, 32));
      if(__any(mt > mrun[qs] + 3.0f)){          // defer-rescale
        float mnew = fmaxf(mrun[qs], mt);
        float a = exp2f(mrun[qs] - mnew);
        mrun[qs] = mnew;
        #pragma unroll
        for(int dt = 0; dt < 9; dt++) acc[qs][dt] = acc[qs][dt] * a;
      }
      float m = mrun[qs];
      unsigned* wp = (unsigned*)&Plds[wid][qs][li][g*4];
      wp[0] = pk2(exp2f(st[qs][0][0] - m), exp2f(st[qs][0][1] - m));
      wp[1] = pk2(exp2f(st[qs][0][2] - m), exp2f(st[qs][0][3] - m));
      wp[8] = pk2(exp2f(st[qs][1][0] - m), exp2f(st[qs][1][1] - m));
      wp[9] = pk2(exp2f(st[qs][1][2] - m), exp2f(st[qs][1][3] - m));
    }

    s16x8 pf0 = *(const s16x8*)&Plds[wid][0][li][g*8];
    s16x8 pf1 = *(const s16x8*)&Plds[wid][1][li][g*8];
    #pragma unroll
    for(int dt = 0; dt < 9; dt++){
      s16x8 vf = *(const s16x8*)(Vp + (dt*16 + li)*(size_t)SC + g*8);
      acc[0][dt] = mfma16(vf, pf0, acc[0][dt]);
      acc[1][dt] = mfma16(vf, pf1, acc[1][dt]);
    }
    Kp += 32*DH;
    Vp += 32;
  }

  if(lane < 16){ sM[wid][0][li] = mrun[0]; sM[wid][1][li] = mrun[1]; }
  // top half: d=64..127 (dt 4..7) + l row (idx 64)
  #pragma unroll
  for(int qs = 0; qs < 2; qs++){
    #pragma unroll
    for(int dt = 4; dt < 8; dt++)
      #pragma unroll
      for(int r = 0; r < 4; r++)
        sOut[wid][(dt-4)*16 + g*4 + r][qs*16 + li] = acc[qs][dt][r];
    if(g == 0) sOut[wid][64][qs*16 + li] = acc[qs][8][0];
  }
  __syncthreads();

  const int q  = threadIdx.x >> 3;
  const int dsub = threadIdx.x & 7;
  {
    float m0 = sM[0][q>>4][q&15], m1 = sM[1][q>>4][q&15], m2 = sM[2][q>>4][q&15], m3 = sM[3][q>>4][q&15];
    float M = fmaxf(fmaxf(m0, m1), fmaxf(m2, m3));
    float a0 = exp2f(m0 - M), a1 = exp2f(m1 - M), a2 = exp2f(m2 - M), a3 = exp2f(m3 - M);
    float Lt = a0*sOut[0][64][q] + a1*sOut[1][64][q] + a2*sOut[2][64][q] + a3*sOut[3][64][q];
    float inv = 1.f / Lt;
    float b0 = a0*inv, b1 = a1*inv, b2 = a2*inv, b3 = a3*inv;
    if(dsub == 0){ sB[0][q] = b0; sB[1][q] = b1; sB[2][q] = b2; sB[3][q] = b3; }
    float* op = AO + ((size_t)b*NQ + q0 + q)*DH + 64 + dsub*8;
    #pragma unroll
    for(int i = 0; i < 8; i++){
      int d = dsub*8 + i;
      op[i] = b0*sOut[0][d][q] + b1*sOut[1][d][q] + b2*sOut[2][d][q] + b3*sOut[3][d][q];
    }
  }
  __syncthreads();
  // bottom half: d=0..63 (dt 0..3)
  #pragma unroll
  for(int qs = 0; qs < 2; qs++)
    #pragma unroll
    for(int dt = 0; dt < 4; dt++)
      #pragma unroll
      for(int r = 0; r < 4; r++)
        sOut[wid][dt*16 + g*4 + r][qs*16 + li] = acc[qs][dt][r];
  __syncthreads();
  {
    float b0 = sB[0][q], b1 = sB[1][q], b2 = sB[2][q], b3 = sB[3][q];
    float* op = AO + ((size_t)b*NQ + q0 + q)*DH + dsub*8;
    #pragma unroll
    for(int i = 0; i < 8; i++){
      int d = dsub*8 + i;
      op[i] = b0*sOut[0][d][q] + b1*sOut[1][d][q] + b2*sOut[2][d][q] + b3*sOut[3][d][q];
    }
  }
}

// ---------------- final part 1: inverse rotary + partial mean over 32-query chunks ----------------
__global__ __launch_bounds__(256) void k_fin1(const float* __restrict__ AO, const float* __restrict__ rq,
                                              float* __restrict__ part){
  __shared__ float red[2][128];
  const int b = blockIdx.y, ch = blockIdx.x;
  const int t = threadIdx.x;
  const int d = t & 127, h = t >> 7;
  float acc = 0.f;
  #pragma unroll 4
  for(int i = 0; i < 16; i++){
    int n = ch*32 + h*16 + i;
    const float* ap = AO + ((size_t)b*NQ + n)*DH;
    float x = ap[d], p = ap[d ^ 1];
    float f = rq[((size_t)b*NQ + n)*DH + d];
    float sn, cs; __sincosf(f, &sn, &cs);
    acc += (d & 1) ? (x*cs - p*sn) : (x*cs + p*sn);   // rotary with -f
  }
  red[h][d] = acc;
  __syncthreads();
  if(h == 0) part[((size_t)b*32 + ch)*128 + d] = red[0][d] + red[1][d];
}

// ---------------- final part 2: reduce chunks + @ w_o^T + b_o ----------------
__global__ __launch_bounds__(256) void k_fin2(const float* __restrict__ part,
                                              const float* __restrict__ wo, const float* __restrict__ bo,
                                              float* __restrict__ out){
  __shared__ float sm[128];
  const int b = blockIdx.x, t = threadIdx.x;
  if(t < 128){
    float s = 0.f;
    for(int ch = 0; ch < 32; ch++) s += part[((size_t)b*32 + ch)*128 + t];
    sm[t] = s * (1.0f / NQ);
  }
  __syncthreads();
  for(int o = t; o < DIM; o += 256){
    float s = bo[o];
    const float* wr = wo + o*DH;
    #pragma unroll 4
    for(int j = 0; j < DH; j++) s += sm[j] * wr[j];
    out[b*DIM + o] = s;
  }
}

extern "C" void kernel_launch(void* const* d_in, const int* in_sizes, int n_in,
                              void* d_out, int out_size, void* d_ws, size_t ws_size,
                              hipStream_t stream){
  const float* xq   = (const float*)d_in[0];
  const float* xc   = (const float*)d_in[1];
  const float* rq   = (const float*)d_in[2];
  const float* rc   = (const float*)d_in[3];
  const unsigned char* mask = (const unsigned char*)d_in[4];
  const float* lnqw = (const float*)d_in[5];
  const float* lnqb = (const float*)d_in[6];
  const float* lncw = (const float*)d_in[7];
  const float* lncb = (const float*)d_in[8];
  const float* wq   = (const float*)d_in[9];
  const float* wkv  = (const float*)d_in[10];
  const float* wo   = (const float*)d_in[11];
  const float* bo   = (const float*)d_in[12];
  float* out = (float*)d_out;

  char* ws = (char*)d_ws;
  size_t off = 0;
  auto alloc = [&](size_t bytes){ void* p = ws + off; off += (bytes + 255) & ~(size_t)255; return p; };
  float*    Q0   = (float*)   alloc((size_t)NQ*DH*4);
  short*    wqb  = (short*)   alloc((size_t)128*512*2);
  short*    wkvb = (short*)   alloc((size_t)256*256*2);
  unsigned* bits = (unsigned*)alloc((size_t)NB*64*4);
  short*    Kd   = (short*)   alloc((size_t)NB*SC*DH*2);
  short*    Vt   = (short*)   alloc((size_t)NB*VROWS*SC*2);
  float*    AO   = (float*)   alloc((size_t)NB*NQ*DH*4);
  float*    part = (float*)   alloc((size_t)NB*32*128*4);

  k_cvtw  <<<dim3(256),    dim3(256), 0, stream>>>(wq, wkv, wqb, wkvb);
  k_mask  <<<dim3(1),      dim3(256), 0, stream>>>(mask, bits);
  k_vrow  <<<dim3(16,16),  dim3(256), 0, stream>>>(bits, Vt);
  k_qproj <<<dim3(16),     dim3(256), 0, stream>>>(xq, lnqw, lnqb, wqb, Q0);
  k_kvproj<<<dim3(64,16),  dim3(256), 0, stream>>>(xc, lncw, lncb, wkvb, rc, bits, Kd, Vt);
  k_attn  <<<dim3(512),    dim3(256), 0, stream>>>(Q0, rq, Kd, Vt, AO);
  k_fin1  <<<dim3(32,16),  dim3(256), 0, stream>>>(AO, rq, part);
  k_fin2  <<<dim3(16),     dim3(256), 0, stream>>>(part, wo, bo, out);
}

// Round 3
// 494.127 us; speedup vs baseline: 1.3448x; 1.0782x over previous
//
#include <hip/hip_runtime.h>
#include <hip/hip_bf16.h>

// RotaryCrossAttention on MI355X (gfx950).
// v3: k_attn latency attack — Vt row stride padded to 8224 (breaks 16KB L2
//     set aliasing), 2x key-split (grid 1024, merged in k_fin1), P exchange
//     via ds_bpermute (no LDS round-trip / lgkmcnt drain), V loads hoisted.
// Pipeline: k_cvtw ; k_mask ; k_vrow ; k_qproj ; k_kvproj ; k_attn(1024 blk,
//           partial O,m,l) ; k_fin1 (merge halves + inv-rotary + mean) ; k_fin2

#define DEV static __device__ __forceinline__

typedef __attribute__((ext_vector_type(4))) float f32x4;
typedef __attribute__((ext_vector_type(8))) short s16x8;
typedef __attribute__((ext_vector_type(4))) unsigned u32x4;

constexpr int NB   = 16;
constexpr int NQ   = 1024;
constexpr int SC   = 8192;   // T*C
constexpr int DIM  = 512;
constexpr int CDIM = 256;
constexpr int DH   = 128;
constexpr int VROWS = 144;     // 128 V rows + row128 = mask ones + 15 dead rows
constexpr int VSTRIDE = 8224;  // 8192 + 32: 16,448B row stride = 257 lines (kills set aliasing)

DEV short f2bf(float x){
  unsigned u = __builtin_bit_cast(unsigned, x);
  unsigned r = (u + 0x7FFFu + ((u >> 16) & 1u)) >> 16;
  return (short)r;
}

DEV unsigned pk2(float a, float b){
  unsigned short ua = __builtin_bit_cast(unsigned short, __float2bfloat16(a));
  unsigned short ub = __builtin_bit_cast(unsigned short, __float2bfloat16(b));
  return (unsigned)ua | ((unsigned)ub << 16);
}

DEV f32x4 mfma16(s16x8 a, s16x8 b, f32x4 c){
  return __builtin_amdgcn_mfma_f32_16x16x32_bf16(a, b, c, 0, 0, 0);
}

// P cross-lane exchange: C-layout (k=16ks+4g+r rows, q=li col) -> B-frag
// (lane(g,li) holds P[k=g*8+j][q=li], j=0..7). Sources: lane a0=(g&1)*32+li
// (j<4) and a1=a0+16 (j>=4), selecting ks'=g>>1.
DEV s16x8 pexch(int ia0, int ia1, bool hi, unsigned L0, unsigned H0, unsigned L1, unsigned H1){
  int aL0 = __builtin_amdgcn_ds_bpermute(ia0, (int)L0);
  int aL1 = __builtin_amdgcn_ds_bpermute(ia0, (int)L1);
  int aH0 = __builtin_amdgcn_ds_bpermute(ia0, (int)H0);
  int aH1 = __builtin_amdgcn_ds_bpermute(ia0, (int)H1);
  int bL0 = __builtin_amdgcn_ds_bpermute(ia1, (int)L0);
  int bL1 = __builtin_amdgcn_ds_bpermute(ia1, (int)L1);
  int bH0 = __builtin_amdgcn_ds_bpermute(ia1, (int)H0);
  int bH1 = __builtin_amdgcn_ds_bpermute(ia1, (int)H1);
  u32x4 r;
  r[0] = (unsigned)(hi ? aL1 : aL0);
  r[1] = (unsigned)(hi ? aH1 : aH0);
  r[2] = (unsigned)(hi ? bL1 : bL0);
  r[3] = (unsigned)(hi ? bH1 : bH0);
  return __builtin_bit_cast(s16x8, r);
}

// ---------------- weights f32 -> bf16 ----------------
__global__ void k_cvtw(const float* __restrict__ wq, const float* __restrict__ wkv,
                       short* __restrict__ wqb, short* __restrict__ wkvb){
  int i = blockIdx.x * 256 + threadIdx.x;
  if(i < 128*512) wqb[i]  = f2bf(wq[i]);
  if(i < 256*256) wkvb[i] = f2bf(wkv[i]);
}

// ---------------- mask: detect bool(1B) vs int32(4B), pack to bits ----------------
__global__ void k_mask(const unsigned char* __restrict__ raw, unsigned* __restrict__ bits){
  int t = threadIdx.x;
  int nz = 0;
  for(int i = t; i < 8192; i += 256){
    unsigned w = ((const unsigned*)raw)[i];
    if(w & 0xFFFFFF00u) nz = 1;
  }
  int any = __syncthreads_or(nz);
  bool isInt = (any == 0);
  for(int wi = t; wi < NB*2048/32; wi += 256){
    unsigned out = 0;
    if(isInt){
      const int* p = (const int*)raw;
      for(int j = 0; j < 32; j++) out |= (unsigned)(p[wi*32+j] != 0) << j;
    } else {
      for(int j = 0; j < 32; j++) out |= (unsigned)(raw[wi*32+j] != 0) << j;
    }
    bits[wi] = out;
  }
}

// ---------------- Vt row 128 = mask as bf16 ones ----------------
__global__ void k_vrow(const unsigned* __restrict__ bits, short* __restrict__ Vt){
  int b = blockIdx.y;
  int s = blockIdx.x * 512 + threadIdx.x * 2;
  unsigned w = bits[b*64 + ((s & 2047) >> 5)];
  short2 v;
  v.x = ((w >> ( s      & 31)) & 1u) ? (short)0x3F80 : (short)0;
  v.y = ((w >> ((s + 1) & 31)) & 1u) ? (short)0x3F80 : (short)0;
  *(short2*)(Vt + ((size_t)b*VROWS + 128)*VSTRIDE + s) = v;
}

// ---------------- Q projection: LN + GEMM (1024x512 @ 512x128) ----------------
__global__ __launch_bounds__(256) void k_qproj(const float* __restrict__ xq,
                                               const float* __restrict__ lnw, const float* __restrict__ lnb,
                                               const short* __restrict__ wqb, float* __restrict__ Q0){
  const int wid = threadIdx.x >> 6, lane = threadIdx.x & 63;
  const int g = lane >> 4, li = lane & 15;
  const int row0 = blockIdx.x * 64 + wid * 16;

  float mean = 0.f, rstd = 0.f;
  #pragma unroll
  for(int r = 0; r < 16; r++){
    const float* rp = xq + (row0 + r) * DIM;
    f32x4 a = *(const f32x4*)(rp + lane*8);
    f32x4 b = *(const f32x4*)(rp + lane*8 + 4);
    float s = 0.f, sq = 0.f;
    #pragma unroll
    for(int i = 0; i < 4; i++){ s += a[i] + b[i]; sq += a[i]*a[i] + b[i]*b[i]; }
    #pragma unroll
    for(int o = 32; o > 0; o >>= 1){ s += __shfl_xor(s, o); sq += __shfl_xor(sq, o); }
    if(li == r){
      mean = s / DIM;
      float var = sq / DIM - mean*mean;
      rstd = rsqrtf(var + 1e-5f);
    }
  }

  f32x4 acc[8];
  #pragma unroll
  for(int n = 0; n < 8; n++) acc[n] = f32x4{0.f,0.f,0.f,0.f};

  for(int kc = 0; kc < 16; kc++){
    int kd = kc*32 + g*8;
    const float* rp = xq + (row0 + li)*DIM + kd;
    f32x4 a0 = *(const f32x4*)rp;
    f32x4 a1 = *(const f32x4*)(rp + 4);
    f32x4 w0 = *(const f32x4*)(lnw + kd), w1 = *(const f32x4*)(lnw + kd + 4);
    f32x4 b0 = *(const f32x4*)(lnb + kd), b1 = *(const f32x4*)(lnb + kd + 4);
    s16x8 af;
    #pragma unroll
    for(int i = 0; i < 4; i++){
      af[i]   = f2bf((a0[i] - mean)*rstd*w0[i] + b0[i]);
      af[i+4] = f2bf((a1[i] - mean)*rstd*w1[i] + b1[i]);
    }
    #pragma unroll
    for(int n = 0; n < 8; n++){
      s16x8 bf = *(const s16x8*)(wqb + (n*16 + li)*DIM + kd);
      acc[n] = mfma16(af, bf, acc[n]);
    }
  }
  #pragma unroll
  for(int n = 0; n < 8; n++)
    #pragma unroll
    for(int r = 0; r < 4; r++){
      int m = row0 + g*4 + r;
      Q0[m*DH + n*16 + li] = acc[n][r];
    }
}

// ---------------- KV projection: LN + GEMM + rotary -> K and V^T (V masked) ----------------
__global__ __launch_bounds__(256) void k_kvproj(const float* __restrict__ xc,
                                                const float* __restrict__ lnw, const float* __restrict__ lnb,
                                                const short* __restrict__ wkvb, const float* __restrict__ rc,
                                                const unsigned* __restrict__ bits,
                                                short* __restrict__ Kd, short* __restrict__ Vt){
  __shared__ __align__(16) short Klds[128][136];
  __shared__ __align__(16) short Vtlds[128][136];
  const int wid = threadIdx.x >> 6, lane = threadIdx.x & 63;
  const int g = lane >> 4, li = lane & 15;
  const int b = blockIdx.y;
  const int s0 = blockIdx.x * 128;
  const int ws0 = s0 + wid * 32;

  float mean_s[2], rstd_s[2];
  #pragma unroll
  for(int r = 0; r < 32; r++){
    const float* rp = xc + (b*SC + ws0 + r)*CDIM;
    f32x4 a = *(const f32x4*)(rp + lane*4);
    float s = a[0]+a[1]+a[2]+a[3];
    float sq = a[0]*a[0]+a[1]*a[1]+a[2]*a[2]+a[3]*a[3];
    #pragma unroll
    for(int o = 32; o > 0; o >>= 1){ s += __shfl_xor(s, o); sq += __shfl_xor(sq, o); }
    if(li == (r & 15)){
      float m = s / CDIM;
      float var = sq / CDIM - m*m;
      if((r >> 4) == 0){ mean_s[0] = m; rstd_s[0] = rsqrtf(var + 1e-5f); }
      else             { mean_s[1] = m; rstd_s[1] = rsqrtf(var + 1e-5f); }
    }
  }

  f32x4 acc[16][2];
  #pragma unroll
  for(int n = 0; n < 16; n++){ acc[n][0] = f32x4{0.f,0.f,0.f,0.f}; acc[n][1] = f32x4{0.f,0.f,0.f,0.f}; }

  for(int kc = 0; kc < 8; kc++){
    int kd = kc*32 + g*8;
    f32x4 w0 = *(const f32x4*)(lnw + kd), w1 = *(const f32x4*)(lnw + kd + 4);
    f32x4 b0 = *(const f32x4*)(lnb + kd), b1 = *(const f32x4*)(lnb + kd + 4);
    s16x8 af[2];
    #pragma unroll
    for(int sub = 0; sub < 2; sub++){
      const float* rp = xc + (b*SC + ws0 + sub*16 + li)*CDIM + kd;
      f32x4 a0 = *(const f32x4*)rp;
      f32x4 a1 = *(const f32x4*)(rp + 4);
      float mn = mean_s[sub], rs = rstd_s[sub];
      #pragma unroll
      for(int i = 0; i < 4; i++){
        af[sub][i]   = f2bf((a0[i]-mn)*rs*w0[i] + b0[i]);
        af[sub][i+4] = f2bf((a1[i]-mn)*rs*w1[i] + b1[i]);
      }
    }
    #pragma unroll
    for(int nt = 0; nt < 16; nt++){
      s16x8 bf = *(const s16x8*)(wkvb + (nt*16 + li)*CDIM + kd);
      acc[nt][0] = mfma16(af[0], bf, acc[nt][0]);
      acc[nt][1] = mfma16(af[1], bf, acc[nt][1]);
    }
  }

  // rotary + stage (k rows, v transposed)
  #pragma unroll
  for(int nt = 0; nt < 8; nt++){
    #pragma unroll
    for(int sub = 0; sub < 2; sub++){
      #pragma unroll
      for(int r = 0; r < 4; r++){
        int srow = wid*32 + sub*16 + g*4 + r;      // 0..127
        int d = nt*16 + li;                        // 0..127
        float f = rc[(b*SC + s0 + srow)*DH + d];
        float sn, cs; __sincosf(f, &sn, &cs);
        float kv = acc[nt][sub][r];
        float kp = __shfl_xor(kv, 1);
        float ky = (d & 1) ? (kv*cs + kp*sn) : (kv*cs - kp*sn);
        Klds[srow][d] = f2bf(ky);
        float vv = acc[nt+8][sub][r];
        float vp = __shfl_xor(vv, 1);
        float vy = (d & 1) ? (vv*cs + vp*sn) : (vv*cs - vp*sn);
        Vtlds[d][srow] = f2bf(vy);
      }
    }
  }
  __syncthreads();
  for(int c = threadIdx.x; c < 2048; c += 256){
    int row = c >> 4, col = (c & 15) * 8;
    s16x8 kv = *(const s16x8*)&Klds[row][col];
    *(s16x8*)(Kd + ((size_t)b*SC + s0 + row)*DH + col) = kv;
    s16x8 vv = *(const s16x8*)&Vtlds[row][col];
    int sa = s0 + col;
    unsigned w = bits[b*64 + ((sa & 2047) >> 5)];
    unsigned mb = (w >> (sa & 31)) & 0xFFu;
    #pragma unroll
    for(int j = 0; j < 8; j++) if(!((mb >> j) & 1u)) vv[j] = 0;
    *(s16x8*)(Vt + ((size_t)b*VROWS + row)*VSTRIDE + sa) = vv;
  }
}

// ---------------- attention (partial over half the keys) ----------------
// grid 1024: (b, q0 32-tile, key-half). 4 waves x 1024 keys each, 32 steps.
// Writes unnormalized partial O + (m, l); halves merged in k_fin1.
__global__ __launch_bounds__(256) void k_attn(const float* __restrict__ Q0, const float* __restrict__ rq,
                                              const short* __restrict__ Kd, const short* __restrict__ Vt,
                                              float* __restrict__ AOp, float* __restrict__ ML){
  __shared__ float sOut[4][65][33];
  __shared__ float sM[4][2][16];
  __shared__ float sW[4][32];
  const int wid = threadIdx.x >> 6, lane = threadIdx.x & 63;
  const int g = lane >> 4, li = lane & 15;
  // XCD swizzle: 128 consecutive oids (= 2 full batches) per XCD
  const int oid = (blockIdx.x & 7) * 128 + (blockIdx.x >> 3);
  const int b = oid >> 6;
  const int rem = oid & 63;
  const int q0 = (rem >> 1) * 32;
  const int half = rem & 1;
  const int base = half*4096 + wid*1024;
  constexpr float C2 = 0.08838834764831845f * 1.4426950408889634f; // scale * log2(e)

  // Q fragments with rotary applied, pre-scaled by C2, bf16
  s16x8 qf[2][4];
  #pragma unroll
  for(int qs = 0; qs < 2; qs++){
    int qrow = q0 + qs*16 + li;
    #pragma unroll
    for(int c = 0; c < 4; c++){
      int d0 = c*32 + g*8;
      const float* qp = Q0 + qrow*DH + d0;
      const float* fp = rq + (b*NQ + qrow)*DH + d0;
      f32x4 x0 = *(const f32x4*)qp,     x1 = *(const f32x4*)(qp+4);
      f32x4 f0 = *(const f32x4*)fp,     f1 = *(const f32x4*)(fp+4);
      float xs[8] = {x0[0],x0[1],x0[2],x0[3],x1[0],x1[1],x1[2],x1[3]};
      float fs[8] = {f0[0],f0[1],f0[2],f0[3],f1[0],f1[1],f1[2],f1[3]};
      #pragma unroll
      for(int i = 0; i < 4; i++){
        float se, ce, so, co;
        __sincosf(fs[2*i],   &se, &ce);
        __sincosf(fs[2*i+1], &so, &co);
        qf[qs][c][2*i]   = f2bf((xs[2*i]*ce   - xs[2*i+1]*se) * C2);
        qf[qs][c][2*i+1] = f2bf((xs[2*i+1]*co + xs[2*i]*so) * C2);
      }
    }
  }

  float mrun[2] = {-1e30f, -1e30f};
  f32x4 acc[2][9];
  #pragma unroll
  for(int qs = 0; qs < 2; qs++)
    #pragma unroll
    for(int dt = 0; dt < 9; dt++) acc[qs][dt] = f32x4{0.f,0.f,0.f,0.f};

  const short* Kp = Kd + ((size_t)b*SC + base)*DH;
  const short* Vp = Vt + (size_t)b*VROWS*VSTRIDE + base;
  const int ia0 = (((lane >> 4) & 1) * 32 + li) << 2;
  const int ia1 = ia0 + 64;
  const bool hi = (g >= 2);

  for(int t = 0; t < 32; ++t){
    // V for this step — issued first so latency hides under QK + softmax
    s16x8 vf[9];
    #pragma unroll
    for(int dt = 0; dt < 9; dt++)
      vf[dt] = *(const s16x8*)(Vp + (size_t)(dt*16 + li)*VSTRIDE + g*8);
    s16x8 kfa[2][4];
    #pragma unroll
    for(int ks = 0; ks < 2; ks++)
      #pragma unroll
      for(int c = 0; c < 4; c++)
        kfa[ks][c] = *(const s16x8*)(Kp + (ks*16 + li)*DH + c*32 + g*8);

    f32x4 st[2][2];
    #pragma unroll
    for(int qs = 0; qs < 2; qs++)
      #pragma unroll
      for(int ks = 0; ks < 2; ks++){
        f32x4 s = f32x4{0.f,0.f,0.f,0.f};
        #pragma unroll
        for(int c = 0; c < 4; c++) s = mfma16(kfa[ks][c], qf[qs][c], s);
        st[qs][ks] = s;
      }

    s16x8 pf[2];
    #pragma unroll
    for(int qs = 0; qs < 2; qs++){
      float mt = fmaxf(fmaxf(fmaxf(st[qs][0][0], st[qs][0][1]), fmaxf(st[qs][0][2], st[qs][0][3])),
                       fmaxf(fmaxf(st[qs][1][0], st[qs][1][1]), fmaxf(st[qs][1][2], st[qs][1][3])));
      mt = fmaxf(mt, __shfl_xor(mt, 16));
      mt = fmaxf(mt, __shfl_xor(mt, 32));
      if(__any(mt > mrun[qs] + 3.0f)){          // defer-rescale
        float mnew = fmaxf(mrun[qs], mt);
        float a = exp2f(mrun[qs] - mnew);
        mrun[qs] = mnew;
        #pragma unroll
        for(int dt = 0; dt < 9; dt++) acc[qs][dt] = acc[qs][dt] * a;
      }
      float m = mrun[qs];
      unsigned L0 = pk2(exp2f(st[qs][0][0] - m), exp2f(st[qs][0][1] - m));
      unsigned H0 = pk2(exp2f(st[qs][0][2] - m), exp2f(st[qs][0][3] - m));
      unsigned L1 = pk2(exp2f(st[qs][1][0] - m), exp2f(st[qs][1][1] - m));
      unsigned H1 = pk2(exp2f(st[qs][1][2] - m), exp2f(st[qs][1][3] - m));
      pf[qs] = pexch(ia0, ia1, hi, L0, H0, L1, H1);
    }

    #pragma unroll
    for(int dt = 0; dt < 9; dt++){
      acc[0][dt] = mfma16(vf[dt], pf[0], acc[0][dt]);
      acc[1][dt] = mfma16(vf[dt], pf[1], acc[1][dt]);
    }
    Kp += 32*DH;
    Vp += 32;
  }

  if(lane < 16){ sM[wid][0][li] = mrun[0]; sM[wid][1][li] = mrun[1]; }
  // phase A: d=64..127 (dt 4..7) + l row (idx 64)
  #pragma unroll
  for(int qs = 0; qs < 2; qs++){
    #pragma unroll
    for(int dt = 4; dt < 8; dt++)
      #pragma unroll
      for(int r = 0; r < 4; r++)
        sOut[wid][(dt-4)*16 + g*4 + r][qs*16 + li] = acc[qs][dt][r];
    if(g == 0) sOut[wid][64][qs*16 + li] = acc[qs][8][0];
  }
  __syncthreads();

  const int q  = threadIdx.x >> 3;
  const int dsub = threadIdx.x & 7;
  const size_t obase = ((size_t)(half*NB + b)*NQ + q0 + q);
  {
    float m0 = sM[0][q>>4][q&15], m1 = sM[1][q>>4][q&15], m2 = sM[2][q>>4][q&15], m3 = sM[3][q>>4][q&15];
    float M = fmaxf(fmaxf(m0, m1), fmaxf(m2, m3));
    float w0 = exp2f(m0 - M), w1 = exp2f(m1 - M), w2 = exp2f(m2 - M), w3 = exp2f(m3 - M);
    float Lb = w0*sOut[0][64][q] + w1*sOut[1][64][q] + w2*sOut[2][64][q] + w3*sOut[3][64][q];
    if(dsub == 0){
      sW[0][q] = w0; sW[1][q] = w1; sW[2][q] = w2; sW[3][q] = w3;
      ML[obase*2]   = M;
      ML[obase*2+1] = Lb;
    }
    float* op = AOp + obase*DH + 64 + dsub*8;
    #pragma unroll
    for(int i = 0; i < 8; i++){
      int d = dsub*8 + i;
      op[i] = w0*sOut[0][d][q] + w1*sOut[1][d][q] + w2*sOut[2][d][q] + w3*sOut[3][d][q];
    }
  }
  __syncthreads();
  // phase B: d=0..63 (dt 0..3)
  #pragma unroll
  for(int qs = 0; qs < 2; qs++)
    #pragma unroll
    for(int dt = 0; dt < 4; dt++)
      #pragma unroll
      for(int r = 0; r < 4; r++)
        sOut[wid][dt*16 + g*4 + r][qs*16 + li] = acc[qs][dt][r];
  __syncthreads();
  {
    float w0 = sW[0][q], w1 = sW[1][q], w2 = sW[2][q], w3 = sW[3][q];
    float* op = AOp + obase*DH + dsub*8;
    #pragma unroll
    for(int i = 0; i < 8; i++){
      int d = dsub*8 + i;
      op[i] = w0*sOut[0][d][q] + w1*sOut[1][d][q] + w2*sOut[2][d][q] + w3*sOut[3][d][q];
    }
  }
}

// ---------------- final part 1: merge key-halves + inverse rotary + partial mean ----------------
__global__ __launch_bounds__(256) void k_fin1(const float* __restrict__ AOp, const float* __restrict__ ML,
                                              const float* __restrict__ rq, float* __restrict__ part){
  __shared__ float red[2][128];
  const int b = blockIdx.y, ch = blockIdx.x;
  const int t = threadIdx.x;
  const int d = t & 127, h = t >> 7;
  float acc = 0.f;
  #pragma unroll 4
  for(int i = 0; i < 16; i++){
    int n = ch*32 + h*16 + i;
    size_t i0 = ((size_t)b*NQ + n);
    size_t i1 = ((size_t)(NB + b)*NQ + n);
    float m0 = ML[i0*2], l0 = ML[i0*2+1];
    float m1 = ML[i1*2], l1 = ML[i1*2+1];
    float M = fmaxf(m0, m1);
    float w0 = exp2f(m0 - M), w1 = exp2f(m1 - M);
    float inv = 1.f / (w0*l0 + w1*l1);
    float O = (w0*AOp[i0*DH + d] + w1*AOp[i1*DH + d]) * inv;
    float P = __shfl_xor(O, 1);
    float f = rq[i0*DH + d];
    float sn, cs; __sincosf(f, &sn, &cs);
    acc += (d & 1) ? (O*cs - P*sn) : (O*cs + P*sn);   // rotary with -f
  }
  red[h][d] = acc;
  __syncthreads();
  if(h == 0) part[((size_t)b*32 + ch)*128 + d] = red[0][d] + red[1][d];
}

// ---------------- final part 2: reduce chunks + @ w_o^T + b_o ----------------
__global__ __launch_bounds__(256) void k_fin2(const float* __restrict__ part,
                                              const float* __restrict__ wo, const float* __restrict__ bo,
                                              float* __restrict__ out){
  __shared__ float sm[128];
  const int b = blockIdx.x, t = threadIdx.x;
  if(t < 128){
    float s = 0.f;
    for(int ch = 0; ch < 32; ch++) s += part[((size_t)b*32 + ch)*128 + t];
    sm[t] = s * (1.0f / NQ);
  }
  __syncthreads();
  for(int o = t; o < DIM; o += 256){
    float s = bo[o];
    const float* wr = wo + o*DH;
    #pragma unroll 4
    for(int j = 0; j < DH; j++) s += sm[j] * wr[j];
    out[b*DIM + o] = s;
  }
}

extern "C" void kernel_launch(void* const* d_in, const int* in_sizes, int n_in,
                              void* d_out, int out_size, void* d_ws, size_t ws_size,
                              hipStream_t stream){
  const float* xq   = (const float*)d_in[0];
  const float* xc   = (const float*)d_in[1];
  const float* rq   = (const float*)d_in[2];
  const float* rc   = (const float*)d_in[3];
  const unsigned char* mask = (const unsigned char*)d_in[4];
  const float* lnqw = (const float*)d_in[5];
  const float* lnqb = (const float*)d_in[6];
  const float* lncw = (const float*)d_in[7];
  const float* lncb = (const float*)d_in[8];
  const float* wq   = (const float*)d_in[9];
  const float* wkv  = (const float*)d_in[10];
  const float* wo   = (const float*)d_in[11];
  const float* bo   = (const float*)d_in[12];
  float* out = (float*)d_out;

  char* ws = (char*)d_ws;
  size_t off = 0;
  auto alloc = [&](size_t bytes){ void* p = ws + off; off += (bytes + 255) & ~(size_t)255; return p; };
  float*    Q0   = (float*)   alloc((size_t)NQ*DH*4);
  short*    wqb  = (short*)   alloc((size_t)128*512*2);
  short*    wkvb = (short*)   alloc((size_t)256*256*2);
  unsigned* bits = (unsigned*)alloc((size_t)NB*64*4);
  short*    Kd   = (short*)   alloc((size_t)NB*SC*DH*2);
  short*    Vt   = (short*)   alloc((size_t)NB*VROWS*VSTRIDE*2);
  float*    AOp  = (float*)   alloc((size_t)2*NB*NQ*DH*4);
  float*    ML   = (float*)   alloc((size_t)2*NB*NQ*2*4);
  float*    part = (float*)   alloc((size_t)NB*32*128*4);

  k_cvtw  <<<dim3(256),    dim3(256), 0, stream>>>(wq, wkv, wqb, wkvb);
  k_mask  <<<dim3(1),      dim3(256), 0, stream>>>(mask, bits);
  k_vrow  <<<dim3(16,16),  dim3(256), 0, stream>>>(bits, Vt);
  k_qproj <<<dim3(16),     dim3(256), 0, stream>>>(xq, lnqw, lnqb, wqb, Q0);
  k_kvproj<<<dim3(64,16),  dim3(256), 0, stream>>>(xc, lncw, lncb, wkvb, rc, bits, Kd, Vt);
  k_attn  <<<dim3(1024),   dim3(256), 0, stream>>>(Q0, rq, Kd, Vt, AOp, ML);
  k_fin1  <<<dim3(32,16),  dim3(256), 0, stream>>>(AOp, ML, rq, part);
  k_fin2  <<<dim3(16),     dim3(256), 0, stream>>>(part, wo, bo, out);
}

// Round 4
// 474.225 us; speedup vs baseline: 1.4012x; 1.0420x over previous
//
#include <hip/hip_runtime.h>
#include <hip/hip_bf16.h>

// RotaryCrossAttention on MI355X (gfx950).
// v4: k_attn rebuilt per the canonical CDNA attention anatomy:
//     - 4 waves share each 64-key step (wave owns 32 q of a 128-q tile)
//     - K [64][128] and V^T [144][64] tiles staged global->LDS via
//       global_load_lds width-16, XOR-swizzled (byte ^= (row&7)<<4) with
//       pre-swizzled global source; V stored in contiguous 18KB tiles
//     - double-buffered, 2 barriers/step (m97 structure)
//     - waves write disjoint q-rows: no merge LDS; 4 key-quarter partials
//       merged in k_fin1
// Pipeline: k_cvtw ; k_mask(16 blk) ; k_vrow ; k_qproj ; k_kvproj ; k_attn ;
//           k_fin1 ; k_fin2

#define DEV static __device__ __forceinline__

typedef __attribute__((ext_vector_type(4))) float f32x4;
typedef __attribute__((ext_vector_type(8))) short s16x8;
typedef __attribute__((ext_vector_type(4))) unsigned u32x4;

constexpr int NB   = 16;
constexpr int NQ   = 1024;
constexpr int SC   = 8192;   // T*C
constexpr int DIM  = 512;
constexpr int CDIM = 256;
constexpr int DH   = 128;
constexpr int VTR  = 144;    // V tile rows: d 0..127, row128 = mask-ones, 129..143 dead
constexpr int VTILE = VTR*64; // elems per 64-key V tile (18KB)

DEV short f2bf(float x){
  unsigned u = __builtin_bit_cast(unsigned, x);
  unsigned r = (u + 0x7FFFu + ((u >> 16) & 1u)) >> 16;
  return (short)r;
}

DEV unsigned pk2(float a, float b){
  unsigned short ua = __builtin_bit_cast(unsigned short, __float2bfloat16(a));
  unsigned short ub = __builtin_bit_cast(unsigned short, __float2bfloat16(b));
  return (unsigned)ua | ((unsigned)ub << 16);
}

DEV f32x4 mfma16(s16x8 a, s16x8 b, f32x4 c){
  return __builtin_amdgcn_mfma_f32_16x16x32_bf16(a, b, c, 0, 0, 0);
}

DEV void gload16(const void* g, void* l){
  __builtin_amdgcn_global_load_lds(
      (const __attribute__((address_space(1))) void*)g,
      (__attribute__((address_space(3))) void*)l, 16, 0, 0);
}

// P cross-lane exchange (verified v3): C-layout St rows -> PV B-frag.
DEV s16x8 pexch(int ia0, int ia1, bool hi, unsigned L0, unsigned H0, unsigned L1, unsigned H1){
  int aL0 = __builtin_amdgcn_ds_bpermute(ia0, (int)L0);
  int aL1 = __builtin_amdgcn_ds_bpermute(ia0, (int)L1);
  int aH0 = __builtin_amdgcn_ds_bpermute(ia0, (int)H0);
  int aH1 = __builtin_amdgcn_ds_bpermute(ia0, (int)H1);
  int bL0 = __builtin_amdgcn_ds_bpermute(ia1, (int)L0);
  int bL1 = __builtin_amdgcn_ds_bpermute(ia1, (int)L1);
  int bH0 = __builtin_amdgcn_ds_bpermute(ia1, (int)H0);
  int bH1 = __builtin_amdgcn_ds_bpermute(ia1, (int)H1);
  u32x4 r;
  r[0] = (unsigned)(hi ? aL1 : aL0);
  r[1] = (unsigned)(hi ? aH1 : aH0);
  r[2] = (unsigned)(hi ? bL1 : bL0);
  r[3] = (unsigned)(hi ? bH1 : bH0);
  return __builtin_bit_cast(s16x8, r);
}

// ---------------- weights f32 -> bf16 ----------------
__global__ void k_cvtw(const float* __restrict__ wq, const float* __restrict__ wkv,
                       short* __restrict__ wqb, short* __restrict__ wkvb){
  int i = blockIdx.x * 256 + threadIdx.x;
  if(i < 128*512) wqb[i]  = f2bf(wq[i]);
  if(i < 256*256) wkvb[i] = f2bf(wkv[i]);
}

// ---------------- mask: detect bool(1B) vs int32(4B), pack to bits ----------------
__global__ void k_mask(const unsigned char* __restrict__ raw, unsigned* __restrict__ bits){
  const int b = blockIdx.x, t = threadIdx.x;
  int nz = 0;
  for(int i = t; i < 8192; i += 256){       // first 32KB valid under both layouts
    unsigned w = ((const unsigned*)raw)[i];
    if(w & 0xFFFFFF00u) nz = 1;
  }
  int any = __syncthreads_or(nz);
  bool isInt = (any == 0);
  if(t < 64){
    unsigned out = 0;
    if(isInt){
      const int* p = (const int*)raw + (b*2048 + t*32);
      for(int j = 0; j < 32; j++) out |= (unsigned)(p[j] != 0) << j;
    } else {
      const unsigned char* p = raw + (b*2048 + t*32);
      for(int j = 0; j < 32; j++) out |= (unsigned)(p[j] != 0) << j;
    }
    bits[b*64 + t] = out;
  }
}

// ---------------- V tile row 128 = mask as bf16 ones ----------------
__global__ void k_vrow(const unsigned* __restrict__ bits, short* __restrict__ Vt){
  int b = blockIdx.y;
  int s = blockIdx.x * 256 + threadIdx.x;    // 0..8191
  unsigned w = bits[b*64 + ((s & 2047) >> 5)];
  short v = ((w >> (s & 31)) & 1u) ? (short)0x3F80 : (short)0;
  Vt[(((size_t)b*128 + (s >> 6))*VTR + 128)*64 + (s & 63)] = v;
}

// ---------------- Q projection: LN + GEMM (1024x512 @ 512x128) ----------------
__global__ __launch_bounds__(256) void k_qproj(const float* __restrict__ xq,
                                               const float* __restrict__ lnw, const float* __restrict__ lnb,
                                               const short* __restrict__ wqb, float* __restrict__ Q0){
  const int wid = threadIdx.x >> 6, lane = threadIdx.x & 63;
  const int g = lane >> 4, li = lane & 15;
  const int row0 = blockIdx.x * 64 + wid * 16;

  float mean = 0.f, rstd = 0.f;
  #pragma unroll
  for(int r = 0; r < 16; r++){
    const float* rp = xq + (row0 + r) * DIM;
    f32x4 a = *(const f32x4*)(rp + lane*8);
    f32x4 b = *(const f32x4*)(rp + lane*8 + 4);
    float s = 0.f, sq = 0.f;
    #pragma unroll
    for(int i = 0; i < 4; i++){ s += a[i] + b[i]; sq += a[i]*a[i] + b[i]*b[i]; }
    #pragma unroll
    for(int o = 32; o > 0; o >>= 1){ s += __shfl_xor(s, o); sq += __shfl_xor(sq, o); }
    if(li == r){
      mean = s / DIM;
      float var = sq / DIM - mean*mean;
      rstd = rsqrtf(var + 1e-5f);
    }
  }

  f32x4 acc[8];
  #pragma unroll
  for(int n = 0; n < 8; n++) acc[n] = f32x4{0.f,0.f,0.f,0.f};

  for(int kc = 0; kc < 16; kc++){
    int kd = kc*32 + g*8;
    const float* rp = xq + (row0 + li)*DIM + kd;
    f32x4 a0 = *(const f32x4*)rp;
    f32x4 a1 = *(const f32x4*)(rp + 4);
    f32x4 w0 = *(const f32x4*)(lnw + kd), w1 = *(const f32x4*)(lnw + kd + 4);
    f32x4 b0 = *(const f32x4*)(lnb + kd), b1 = *(const f32x4*)(lnb + kd + 4);
    s16x8 af;
    #pragma unroll
    for(int i = 0; i < 4; i++){
      af[i]   = f2bf((a0[i] - mean)*rstd*w0[i] + b0[i]);
      af[i+4] = f2bf((a1[i] - mean)*rstd*w1[i] + b1[i]);
    }
    #pragma unroll
    for(int n = 0; n < 8; n++){
      s16x8 bf = *(const s16x8*)(wqb + (n*16 + li)*DIM + kd);
      acc[n] = mfma16(af, bf, acc[n]);
    }
  }
  #pragma unroll
  for(int n = 0; n < 8; n++)
    #pragma unroll
    for(int r = 0; r < 4; r++){
      int m = row0 + g*4 + r;
      Q0[m*DH + n*16 + li] = acc[n][r];
    }
}

// ---------------- KV projection: LN + GEMM + rotary -> K rows and V tiles ----------------
__global__ __launch_bounds__(256) void k_kvproj(const float* __restrict__ xc,
                                                const float* __restrict__ lnw, const float* __restrict__ lnb,
                                                const short* __restrict__ wkvb, const float* __restrict__ rc,
                                                const unsigned* __restrict__ bits,
                                                short* __restrict__ Kd, short* __restrict__ Vt){
  __shared__ __align__(16) short Klds[128][136];
  __shared__ __align__(16) short Vtlds[128][136];
  const int wid = threadIdx.x >> 6, lane = threadIdx.x & 63;
  const int g = lane >> 4, li = lane & 15;
  const int b = blockIdx.y;
  const int s0 = blockIdx.x * 128;
  const int ws0 = s0 + wid * 32;

  float mean_s[2], rstd_s[2];
  #pragma unroll
  for(int r = 0; r < 32; r++){
    const float* rp = xc + (b*SC + ws0 + r)*CDIM;
    f32x4 a = *(const f32x4*)(rp + lane*4);
    float s = a[0]+a[1]+a[2]+a[3];
    float sq = a[0]*a[0]+a[1]*a[1]+a[2]*a[2]+a[3]*a[3];
    #pragma unroll
    for(int o = 32; o > 0; o >>= 1){ s += __shfl_xor(s, o); sq += __shfl_xor(sq, o); }
    if(li == (r & 15)){
      float m = s / CDIM;
      float var = sq / CDIM - m*m;
      if((r >> 4) == 0){ mean_s[0] = m; rstd_s[0] = rsqrtf(var + 1e-5f); }
      else             { mean_s[1] = m; rstd_s[1] = rsqrtf(var + 1e-5f); }
    }
  }

  f32x4 acc[16][2];
  #pragma unroll
  for(int n = 0; n < 16; n++){ acc[n][0] = f32x4{0.f,0.f,0.f,0.f}; acc[n][1] = f32x4{0.f,0.f,0.f,0.f}; }

  for(int kc = 0; kc < 8; kc++){
    int kd = kc*32 + g*8;
    f32x4 w0 = *(const f32x4*)(lnw + kd), w1 = *(const f32x4*)(lnw + kd + 4);
    f32x4 b0 = *(const f32x4*)(lnb + kd), b1 = *(const f32x4*)(lnb + kd + 4);
    s16x8 af[2];
    #pragma unroll
    for(int sub = 0; sub < 2; sub++){
      const float* rp = xc + (b*SC + ws0 + sub*16 + li)*CDIM + kd;
      f32x4 a0 = *(const f32x4*)rp;
      f32x4 a1 = *(const f32x4*)(rp + 4);
      float mn = mean_s[sub], rs = rstd_s[sub];
      #pragma unroll
      for(int i = 0; i < 4; i++){
        af[sub][i]   = f2bf((a0[i]-mn)*rs*w0[i] + b0[i]);
        af[sub][i+4] = f2bf((a1[i]-mn)*rs*w1[i] + b1[i]);
      }
    }
    #pragma unroll
    for(int nt = 0; nt < 16; nt++){
      s16x8 bf = *(const s16x8*)(wkvb + (nt*16 + li)*CDIM + kd);
      acc[nt][0] = mfma16(af[0], bf, acc[nt][0]);
      acc[nt][1] = mfma16(af[1], bf, acc[nt][1]);
    }
  }

  // rotary + stage (k rows, v transposed)
  #pragma unroll
  for(int nt = 0; nt < 8; nt++){
    #pragma unroll
    for(int sub = 0; sub < 2; sub++){
      #pragma unroll
      for(int r = 0; r < 4; r++){
        int srow = wid*32 + sub*16 + g*4 + r;      // 0..127
        int d = nt*16 + li;                        // 0..127
        float f = rc[(b*SC + s0 + srow)*DH + d];
        float sn, cs; __sincosf(f, &sn, &cs);
        float kv = acc[nt][sub][r];
        float kp = __shfl_xor(kv, 1);
        float ky = (d & 1) ? (kv*cs + kp*sn) : (kv*cs - kp*sn);
        Klds[srow][d] = f2bf(ky);
        float vv = acc[nt+8][sub][r];
        float vp = __shfl_xor(vv, 1);
        float vy = (d & 1) ? (vv*cs + vp*sn) : (vv*cs - vp*sn);
        Vtlds[d][srow] = f2bf(vy);
      }
    }
  }
  __syncthreads();
  for(int c = threadIdx.x; c < 2048; c += 256){
    int row = c >> 4, col = (c & 15) * 8;
    s16x8 kv = *(const s16x8*)&Klds[row][col];
    *(s16x8*)(Kd + ((size_t)b*SC + s0 + row)*DH + col) = kv;
    s16x8 vv = *(const s16x8*)&Vtlds[row][col];
    int sa = s0 + col;
    unsigned w = bits[b*64 + ((sa & 2047) >> 5)];
    unsigned mb = (w >> (sa & 31)) & 0xFFu;
    #pragma unroll
    for(int j = 0; j < 8; j++) if(!((mb >> j) & 1u)) vv[j] = 0;
    *(s16x8*)(Vt + (((size_t)b*128 + (sa >> 6))*VTR + row)*64 + (sa & 63)) = vv;
  }
}

// ---------------- attention ----------------
// grid 512 = b(16) x qt(8) x kq(4); block = 4 waves, each owns 32 q rows of a
// 128-q tile; all waves share 64-key steps staged in LDS (double-buffered,
// XOR-swizzled). 32 steps of 64 keys (2048 = one key-quarter).
__global__ __launch_bounds__(256) void k_attn(const float* __restrict__ Q0, const float* __restrict__ rq,
                                              const short* __restrict__ Kd, const short* __restrict__ Vt,
                                              float* __restrict__ AOp, float* __restrict__ ML){
  __shared__ __align__(16) short Kbuf[2][64*128];   // 2 x 16KB
  __shared__ __align__(16) short Vbuf[2][VTR*64];   // 2 x 18KB
  const int wid = threadIdx.x >> 6, lane = threadIdx.x & 63;
  const int g = lane >> 4, li = lane & 15;
  // XCD-grouped decode: each XCD gets 2 batches, kq-major then q-tiles
  const int xcd = blockIdx.x & 7, ii = blockIdx.x >> 3;
  const int b  = xcd*2 + (ii >> 5);
  const int kq = (ii >> 3) & 3;
  const int qt = ii & 7;
  const int qw0 = qt*128 + wid*32;
  constexpr float C2 = 0.08838834764831845f * 1.4426950408889634f; // scale * log2(e)

  // Q fragments with rotary applied, pre-scaled by C2, bf16
  s16x8 qf[2][4];
  #pragma unroll
  for(int qs = 0; qs < 2; qs++){
    int qrow = qw0 + qs*16 + li;
    #pragma unroll
    for(int c = 0; c < 4; c++){
      int d0 = c*32 + g*8;
      const float* qp = Q0 + qrow*DH + d0;
      const float* fp = rq + ((size_t)b*NQ + qrow)*DH + d0;
      f32x4 x0 = *(const f32x4*)qp,     x1 = *(const f32x4*)(qp+4);
      f32x4 f0 = *(const f32x4*)fp,     f1 = *(const f32x4*)(fp+4);
      float xs[8] = {x0[0],x0[1],x0[2],x0[3],x1[0],x1[1],x1[2],x1[3]};
      float fs[8] = {f0[0],f0[1],f0[2],f0[3],f1[0],f1[1],f1[2],f1[3]};
      #pragma unroll
      for(int i = 0; i < 4; i++){
        float se, ce, so, co;
        __sincosf(fs[2*i],   &se, &ce);
        __sincosf(fs[2*i+1], &so, &co);
        qf[qs][c][2*i]   = f2bf((xs[2*i]*ce   - xs[2*i+1]*se) * C2);
        qf[qs][c][2*i+1] = f2bf((xs[2*i+1]*co + xs[2*i]*so) * C2);
      }
    }
  }

  float mrun[2] = {-1e30f, -1e30f};
  f32x4 acc[2][9];
  #pragma unroll
  for(int qs = 0; qs < 2; qs++)
    #pragma unroll
    for(int dt = 0; dt < 9; dt++) acc[qs][dt] = f32x4{0.f,0.f,0.f,0.f};

  const char* Kg = (const char*)(Kd + ((size_t)b*SC + kq*2048)*DH);   // 256B rows
  const char* Vg = (const char*)(Vt + ((size_t)b*128 + kq*32)*VTILE); // 18KB tiles

  const int ia0 = (((lane >> 4) & 1) * 32 + li) << 2;
  const int ia1 = ia0 + 64;
  const bool hi = (g >= 2);

  // staging: wave stages K rows [wid*16, +16) (4 issues) and V rows
  // [wid*40, +40) for wid<3 / [120,144) for wid==3 (5 or 3 issues).
  const int krp_base = wid*16;
  const int vrp_base = wid*40;     // wave3: 120
  const int nvj = (wid < 3) ? 5 : 3;

  #define STAGE(bufi, t) do{                                                   \
    const char* Ksrc = Kg + (size_t)(t)*64*256;                                \
    _Pragma("unroll")                                                          \
    for(int j = 0; j < 4; j++){                                                \
      int rp = krp_base + j*4 + (lane >> 4);                                   \
      int bi = ((lane & 15)*16) ^ ((rp & 7) << 4);                             \
      gload16(Ksrc + rp*256 + bi, &Kbuf[bufi][(krp_base + j*4)*128]);          \
    }                                                                          \
    const char* Vsrc = Vg + (size_t)(t)*VTILE*2;                               \
    for(int j = 0; j < nvj; j++){                                              \
      int rp = vrp_base + j*8 + (lane >> 3);                                   \
      int bi = ((lane & 7)*16) ^ ((rp & 7) << 4);                              \
      gload16(Vsrc + rp*128 + bi, &Vbuf[bufi][(vrp_base + j*8)*64]);           \
    }                                                                          \
  }while(0)

  STAGE(0, 0);

  for(int t = 0; t < 32; ++t){
    const int cur = t & 1;
    if(t < 31) STAGE(cur^1, t+1);
    __syncthreads();                     // drains vmcnt; both buffers' stages done

    // QK: St[k, q] for 64 keys
    f32x4 st[2][4];
    #pragma unroll
    for(int ks = 0; ks < 4; ks++){
      s16x8 kf[4];
      #pragma unroll
      for(int c = 0; c < 4; c++){
        int row = ks*16 + li;
        int off = row*256 + ((c*64 + g*16) ^ ((row & 7) << 4));
        kf[c] = *(const s16x8*)((const char*)&Kbuf[cur][0] + off);
      }
      #pragma unroll
      for(int qs = 0; qs < 2; qs++){
        f32x4 s = (ks == 0) ? f32x4{0.f,0.f,0.f,0.f} : st[qs][ks-1]*0.f;  // fresh acc
        s = f32x4{0.f,0.f,0.f,0.f};
        #pragma unroll
        for(int c = 0; c < 4; c++) s = mfma16(kf[c], qf[qs][c], s);
        st[qs][ks] = s;
      }
    }

    // softmax + P B-frags
    s16x8 pf[2][2];
    #pragma unroll
    for(int qs = 0; qs < 2; qs++){
      float mt = -1e30f;
      #pragma unroll
      for(int ks = 0; ks < 4; ks++)
        #pragma unroll
        for(int r = 0; r < 4; r++) mt = fmaxf(mt, st[qs][ks][r]);
      mt = fmaxf(mt, __shfl_xor(mt, 16));
      mt = fmaxf(mt, __shfl_xor(mt, 32));
      if(__any(mt > mrun[qs] + 3.0f)){          // defer-rescale
        float mnew = fmaxf(mrun[qs], mt);
        float a = exp2f(mrun[qs] - mnew);
        mrun[qs] = mnew;
        #pragma unroll
        for(int dt = 0; dt < 9; dt++) acc[qs][dt] = acc[qs][dt] * a;
      }
      float m = mrun[qs];
      #pragma unroll
      for(int h2 = 0; h2 < 2; h2++){
        unsigned L0 = pk2(exp2f(st[qs][2*h2][0] - m),   exp2f(st[qs][2*h2][1] - m));
        unsigned H0 = pk2(exp2f(st[qs][2*h2][2] - m),   exp2f(st[qs][2*h2][3] - m));
        unsigned L1 = pk2(exp2f(st[qs][2*h2+1][0] - m), exp2f(st[qs][2*h2+1][1] - m));
        unsigned H1 = pk2(exp2f(st[qs][2*h2+1][2] - m), exp2f(st[qs][2*h2+1][3] - m));
        pf[qs][h2] = pexch(ia0, ia1, hi, L0, H0, L1, H1);
      }
    }

    // PV: acc^T[d, q] += V^T-tile x P
    #pragma unroll
    for(int dt = 0; dt < 9; dt++){
      int row = dt*16 + li;
      #pragma unroll
      for(int k32 = 0; k32 < 2; k32++){
        int off = row*128 + ((k32*64 + g*16) ^ ((row & 7) << 4));
        s16x8 vf = *(const s16x8*)((const char*)&Vbuf[cur][0] + off);
        acc[0][dt] = mfma16(vf, pf[0][k32], acc[0][dt]);
        acc[1][dt] = mfma16(vf, pf[1][k32], acc[1][dt]);
      }
    }
    __syncthreads();                     // all reads done before next stage overwrites
  }

  // epilogue: each wave writes its own 32 q rows (partial O, m, l)
  const size_t pbase = ((size_t)kq*NB + b)*NQ;
  if(lane < 16){
    #pragma unroll
    for(int qs = 0; qs < 2; qs++){
      size_t o = pbase + qw0 + qs*16 + li;
      ML[o*2]   = mrun[qs];
      ML[o*2+1] = acc[qs][8][0];
    }
  }
  #pragma unroll
  for(int qs = 0; qs < 2; qs++){
    size_t o = (pbase + qw0 + qs*16 + li)*DH;
    #pragma unroll
    for(int dt = 0; dt < 8; dt++)
      *(f32x4*)(AOp + o + dt*16 + g*4) = acc[qs][dt];
  }
}

// ---------------- final part 1: merge 4 key-quarters + inverse rotary + partial mean ----------------
__global__ __launch_bounds__(256) void k_fin1(const float* __restrict__ AOp, const float* __restrict__ ML,
                                              const float* __restrict__ rq, float* __restrict__ part){
  __shared__ float red[2][128];
  const int b = blockIdx.y, ch = blockIdx.x;
  const int t = threadIdx.x;
  const int d = t & 127, h = t >> 7;
  float acc = 0.f;
  #pragma unroll 2
  for(int i = 0; i < 16; i++){
    int n = ch*32 + h*16 + i;
    size_t qi = (size_t)b*NQ + n;
    float m[4], l[4];
    #pragma unroll
    for(int kq = 0; kq < 4; kq++){
      size_t o = (size_t)kq*NB*NQ + qi;
      m[kq] = ML[o*2]; l[kq] = ML[o*2+1];
    }
    float M = fmaxf(fmaxf(m[0], m[1]), fmaxf(m[2], m[3]));
    float w[4], L = 0.f;
    #pragma unroll
    for(int kq = 0; kq < 4; kq++){ w[kq] = exp2f(m[kq] - M); L += w[kq]*l[kq]; }
    float inv = 1.f / L;
    float O = 0.f;
    #pragma unroll
    for(int kq = 0; kq < 4; kq++) O += w[kq]*AOp[((size_t)kq*NB*NQ + qi)*DH + d];
    O *= inv;
    float P = __shfl_xor(O, 1);
    float f = rq[qi*DH + d];
    float sn, cs; __sincosf(f, &sn, &cs);
    acc += (d & 1) ? (O*cs - P*sn) : (O*cs + P*sn);   // rotary with -f
  }
  red[h][d] = acc;
  __syncthreads();
  if(h == 0) part[((size_t)b*32 + ch)*128 + d] = red[0][d] + red[1][d];
}

// ---------------- final part 2: reduce chunks + @ w_o^T + b_o ----------------
__global__ __launch_bounds__(256) void k_fin2(const float* __restrict__ part,
                                              const float* __restrict__ wo, const float* __restrict__ bo,
                                              float* __restrict__ out){
  __shared__ float sm[128];
  const int b = blockIdx.x, t = threadIdx.x;
  if(t < 128){
    float s = 0.f;
    for(int ch = 0; ch < 32; ch++) s += part[((size_t)b*32 + ch)*128 + t];
    sm[t] = s * (1.0f / NQ);
  }
  __syncthreads();
  for(int o = t; o < DIM; o += 256){
    float s = bo[o];
    const float* wr = wo + o*DH;
    #pragma unroll 4
    for(int j = 0; j < DH; j++) s += sm[j] * wr[j];
    out[b*DIM + o] = s;
  }
}

extern "C" void kernel_launch(void* const* d_in, const int* in_sizes, int n_in,
                              void* d_out, int out_size, void* d_ws, size_t ws_size,
                              hipStream_t stream){
  const float* xq   = (const float*)d_in[0];
  const float* xc   = (const float*)d_in[1];
  const float* rq   = (const float*)d_in[2];
  const float* rc   = (const float*)d_in[3];
  const unsigned char* mask = (const unsigned char*)d_in[4];
  const float* lnqw = (const float*)d_in[5];
  const float* lnqb = (const float*)d_in[6];
  const float* lncw = (const float*)d_in[7];
  const float* lncb = (const float*)d_in[8];
  const float* wq   = (const float*)d_in[9];
  const float* wkv  = (const float*)d_in[10];
  const float* wo   = (const float*)d_in[11];
  const float* bo   = (const float*)d_in[12];
  float* out = (float*)d_out;

  char* ws = (char*)d_ws;
  size_t off = 0;
  auto alloc = [&](size_t bytes){ void* p = ws + off; off += (bytes + 255) & ~(size_t)255; return p; };
  float*    Q0   = (float*)   alloc((size_t)NQ*DH*4);
  short*    wqb  = (short*)   alloc((size_t)128*512*2);
  short*    wkvb = (short*)   alloc((size_t)256*256*2);
  unsigned* bits = (unsigned*)alloc((size_t)NB*64*4);
  short*    Kd   = (short*)   alloc((size_t)NB*SC*DH*2);          // 32MB
  short*    Vt   = (short*)   alloc((size_t)NB*128*VTILE*2);      // 37.7MB tiled
  float*    AOp  = (float*)   alloc((size_t)4*NB*NQ*DH*4);        // 33.5MB
  float*    ML   = (float*)   alloc((size_t)4*NB*NQ*2*4);
  float*    part = (float*)   alloc((size_t)NB*32*128*4);

  k_cvtw  <<<dim3(256),    dim3(256), 0, stream>>>(wq, wkv, wqb, wkvb);
  k_mask  <<<dim3(16),     dim3(256), 0, stream>>>(mask, bits);
  k_vrow  <<<dim3(32,16),  dim3(256), 0, stream>>>(bits, Vt);
  k_qproj <<<dim3(16),     dim3(256), 0, stream>>>(xq, lnqw, lnqb, wqb, Q0);
  k_kvproj<<<dim3(64,16),  dim3(256), 0, stream>>>(xc, lncw, lncb, wkvb, rc, bits, Kd, Vt);
  k_attn  <<<dim3(512),    dim3(256), 0, stream>>>(Q0, rq, Kd, Vt, AOp, ML);
  k_fin1  <<<dim3(32,16),  dim3(256), 0, stream>>>(AOp, ML, rq, part);
  k_fin2  <<<dim3(16),     dim3(256), 0, stream>>>(part, wo, bo, out);
}